// Round 2
// baseline (1431.602 us; speedup 1.0000x reference)
//
#include <hip/hip_runtime.h>

// ConvSA: B=8, C=256, H=W=48 (N=2304), E=512.
// out[b,e,i] = sum_j softmax_j(q[b,:,i].k[b,:,j]) * v[b,e,j] + v[b,e,i]
// q,k,v = conv3x3(feat, W*) + b*.
//
// Numerics: logits have std ~sqrt(512)=22.6 -> softmax is near-argmax; bf16
// q/k would give logit noise ~0.12 and blow the 0.149 absmax threshold on
// near-tie rows. So q/k convs and QK^T use split-bf16 (x = hi + lo, keep
// hi*hi + hi*lo + lo*hi) => fp32-grade logits. v-conv / PV are plain bf16.

typedef __bf16 bf16;
typedef __bf16 bf16x4 __attribute__((ext_vector_type(4)));
typedef __bf16 bf16x8 __attribute__((ext_vector_type(8)));
typedef float  f32x4  __attribute__((ext_vector_type(4)));
typedef float  f32x16 __attribute__((ext_vector_type(16)));

__device__ __forceinline__ f32x16 mfma16(bf16x8 a, bf16x8 b, f32x16 c) {
  return __builtin_amdgcn_mfma_f32_32x32x16_bf16(a, b, c, 0, 0, 0);
}

#define NB   8
#define NC   256
#define NH   48
#define NN   2304     // 48*48
#define NE   512
#define HP   50       // padded H/W

// ---------------- pack kernels ----------------

// feat NCHW fp32 -> zero-padded NHWC [b][50][50][256] bf16 hi + lo
__global__ void pack_feat(const float* __restrict__ x,
                          bf16* __restrict__ ph, bf16* __restrict__ pl) {
  int idx = blockIdx.x * 256 + threadIdx.x;       // 8*50*50*256 = 5,120,000
  int c  = idx & 255;
  int p  = idx >> 8;                              // b*2500 + yp*50 + xp
  int xp = p % 50; int t = p / 50; int yp = t % 50; int b = t / 50;
  float v = 0.f;
  if (yp >= 1 && yp <= 48 && xp >= 1 && xp <= 48)
    v = x[((b * NC + c) * NH + (yp - 1)) * NH + (xp - 1)];
  bf16 h = (bf16)v;
  ph[idx] = h;
  pl[idx] = (bf16)(v - (float)h);
}

// W OIHW [512][256][3][3] fp32 -> [tap][e][c] bf16: Wq,Wk hi+lo, Wv hi only
__global__ void pack_w(const float* __restrict__ wq, const float* __restrict__ wk,
                       const float* __restrict__ wv,
                       bf16* __restrict__ qh, bf16* __restrict__ ql,
                       bf16* __restrict__ kh, bf16* __restrict__ kl,
                       bf16* __restrict__ vh) {
  int idx = blockIdx.x * 256 + threadIdx.x;       // 9*512*256 = 1,179,648
  int c = idx & 255;
  int r = idx >> 8;                               // t*512 + e
  int e = r & 511; int t = r >> 9;
  int src = (e * NC + c) * 9 + t;
  float a; bf16 h;
  a = wq[src]; h = (bf16)a; qh[idx] = h; ql[idx] = (bf16)(a - (float)h);
  a = wk[src]; h = (bf16)a; kh[idx] = h; kl[idx] = (bf16)(a - (float)h);
  vh[idx] = (bf16)wv[src];
}

// ---------------- implicit-GEMM conv3x3 ----------------
// Block: 256 thr (4 waves). Out tile: 64 e x 384 pos (8 rows x 48).
// Grid (8 e-tiles, 48 = b*6 strips). K-loop: 16 chunks of 16 channels x 9 taps.
// A (W) frags loaded straight from global (L2-resident); X tile staged in LDS,
// NHWC with c-stride 24 (48B rows: aligned b128, 4-way-balanced banks).
// SPLIT: out -> q/k hi+lo at [b][n][e]; else v bf16 at [b][e][n].
template<bool SPLIT>
__global__ __launch_bounds__(256, 2) void conv3(
    const bf16* __restrict__ xh, const bf16* __restrict__ xl,
    const bf16* __restrict__ wh, const bf16* __restrict__ wl,
    const float* __restrict__ bias,
    bf16* __restrict__ oh, bf16* __restrict__ ol, bf16* __restrict__ ot) {
  constexpr int XSZ = 12000;                      // 10*50*24
  __shared__ __align__(16) bf16 sx[SPLIT ? 2 * XSZ : XSZ];
  bf16* sxh = sx;
  bf16* sxl = SPLIT ? (sx + XSZ) : sx;

  const int tid = threadIdx.x;
  const int lane = tid & 63, wv = tid >> 6;
  const int l31 = lane & 31;
  const int koff = (lane >> 5) * 8;
  const int e0 = blockIdx.x * 64;
  const int by = blockIdx.y;
  const int b = by / 6, strip = by % 6;
  const int y0 = strip * 8;

  int pb[3];
#pragma unroll
  for (int nt = 0; nt < 3; ++nt) {
    int n = wv * 96 + nt * 32 + l31;
    pb[nt] = (n / 48) * 50 + (n % 48);
  }

  f32x16 acc[2][3];
#pragma unroll
  for (int mt = 0; mt < 2; ++mt)
#pragma unroll
    for (int nt = 0; nt < 3; ++nt)
#pragma unroll
      for (int i = 0; i < 16; ++i) acc[mt][nt][i] = 0.f;

  for (int cc = 0; cc < 16; ++cc) {
    const int c0 = cc * 16;
    __syncthreads();
    // stage X chunk: 10 rows x 50 cols x 16 ch (hi [+ lo])
    for (int g = tid; g < 1000; g += 256) {
      int p = g >> 1, o = (g & 1) * 8;
      int row = p / 50, xx = p % 50;
      int gidx = ((b * HP + y0 + row) * HP + xx) * NC + c0 + o;
      *(bf16x8*)(sxh + p * 24 + o) = *(const bf16x8*)(xh + gidx);
      if constexpr (SPLIT)
        *(bf16x8*)(sxl + p * 24 + o) = *(const bf16x8*)(xl + gidx);
    }
    __syncthreads();
#pragma unroll
    for (int t = 0; t < 9; ++t) {
      const int dy = t / 3, dx = t % 3;
      const int dpo = (dy * 50 + dx) * 24 + koff;
      bf16x8 bh[3], bl[3];
#pragma unroll
      for (int nt = 0; nt < 3; ++nt) {
        bh[nt] = *(const bf16x8*)(sxh + pb[nt] * 24 + dpo);
        if constexpr (SPLIT) bl[nt] = *(const bf16x8*)(sxl + pb[nt] * 24 + dpo);
      }
#pragma unroll
      for (int mt = 0; mt < 2; ++mt) {
        int widx = ((t * NE) + e0 + mt * 32 + l31) * NC + c0 + koff;
        bf16x8 ah = *(const bf16x8*)(wh + widx);
        if constexpr (SPLIT) {
          bf16x8 al = *(const bf16x8*)(wl + widx);
#pragma unroll
          for (int nt = 0; nt < 3; ++nt) {
            acc[mt][nt] = mfma16(ah, bh[nt], acc[mt][nt]);
            acc[mt][nt] = mfma16(ah, bl[nt], acc[mt][nt]);
            acc[mt][nt] = mfma16(al, bh[nt], acc[mt][nt]);
          }
        } else {
#pragma unroll
          for (int nt = 0; nt < 3; ++nt)
            acc[mt][nt] = mfma16(ah, bh[nt], acc[mt][nt]);
        }
      }
    }
  }

  // epilogue: C/D layout col=lane&31, row=(r&3)+8*(r>>2)+4*(lane>>5)
  const int colh = (lane >> 5) * 4;
#pragma unroll
  for (int mt = 0; mt < 2; ++mt) {
#pragma unroll
    for (int nt = 0; nt < 3; ++nt) {
      int n = wv * 96 + nt * 32 + l31;
      int pos = (y0 + n / 48) * 48 + (n % 48);
#pragma unroll
      for (int g = 0; g < 4; ++g) {
        int eb = e0 + mt * 32 + g * 8 + colh;
        f32x4 bs = *(const f32x4*)(bias + eb);
        if constexpr (SPLIT) {
          bf16x4 h4, l4;
#pragma unroll
          for (int j = 0; j < 4; ++j) {
            float v = acc[mt][nt][g * 4 + j] + bs[j];
            bf16 h = (bf16)v;
            h4[j] = h;
            l4[j] = (bf16)(v - (float)h);
          }
          int oidx = (b * NN + pos) * NE + eb;
          *(bf16x4*)(oh + oidx) = h4;
          *(bf16x4*)(ol + oidx) = l4;
        } else {
#pragma unroll
          for (int j = 0; j < 4; ++j) {
            float v = acc[mt][nt][g * 4 + j] + bs[j];
            ot[(b * NE + eb + j) * NN + pos] = (bf16)v;
          }
        }
      }
    }
  }
}

// ---------------- flash attention ----------------
// Block: 256 thr (4 waves), grid (36 i-tiles, 8 b). i-tile 64, j-tile 128.
// Phase A: S(64x128) via split-bf16 QK^T, e-chunks of 64 staged in LDS
//          (col XOR-swizzle (row&7)*8 -> 4-way-balanced b128 reads).
// Phase B: online softmax (fp32), P -> LDS bf16 [64][136].
// Phase C: PV, v staged [e][j] (32-j chunks, stride 40: 20-bank step, balanced)
//          as B-operand; O 64x128/wave.
__global__ __launch_bounds__(256, 2) void attn(
    const bf16* __restrict__ qh, const bf16* __restrict__ ql,
    const bf16* __restrict__ kh, const bf16* __restrict__ kl,
    const bf16* __restrict__ vt, float* __restrict__ out) {
  __shared__ __align__(16) bf16 smem[24576];  // qh|ql|kh|kl ; Phase C: vt aliases
  __shared__ __align__(16) bf16 sP[64 * 136];
  __shared__ __align__(16) float s_m[64];
  __shared__ __align__(16) float s_l[64];
  __shared__ __align__(16) float s_alpha[64];
  __shared__ __align__(16) float s_red[128];
  bf16* sqh = smem;
  bf16* sql = smem + 4096;
  bf16* skh = smem + 8192;
  bf16* skl = smem + 16384;
  bf16* svt = smem;                                // [512 e][stride 40], aliased

  const int tid = threadIdx.x;
  const int lane = tid & 63, wv = tid >> 6;
  const int l31 = lane & 31, lh = lane >> 5;
  const int mhalf = wv >> 1, npair = wv & 1;
  const int b = blockIdx.y, i0 = blockIdx.x * 64;

  const int qbase = (b * NN + i0) * NE;
  const int kbase = b * NN * NE;
  const int vbase = b * NE * NN;

  if (tid < 64) { s_m[tid] = -3.0e38f; s_l[tid] = 0.f; }

  f32x16 O[2][4];
#pragma unroll
  for (int mt = 0; mt < 2; ++mt)
#pragma unroll
    for (int nt = 0; nt < 4; ++nt)
#pragma unroll
      for (int i = 0; i < 16; ++i) O[mt][nt][i] = 0.f;

  for (int jt = 0; jt < 18; ++jt) {
    const int j0 = jt * 128;
    f32x16 S[2];
#pragma unroll
    for (int nt = 0; nt < 2; ++nt)
#pragma unroll
      for (int i = 0; i < 16; ++i) S[nt][i] = 0.f;

    // ---- Phase A: S = q.k^T over e in chunks of 64 ----
    for (int ec = 0; ec < 8; ++ec) {
      __syncthreads();
#pragma unroll
      for (int r = 0; r < 2; ++r) {                 // q: 64x64 hi+lo
        int g = tid * 2 + r;
        int row = g >> 3, o = (g & 7) * 8;
        int os = o ^ ((row & 7) * 8);
        int gi = qbase + row * NE + ec * 64 + o;
        *(bf16x8*)(sqh + row * 64 + os) = *(const bf16x8*)(qh + gi);
        *(bf16x8*)(sql + row * 64 + os) = *(const bf16x8*)(ql + gi);
      }
#pragma unroll
      for (int r = 0; r < 4; ++r) {                 // k: 128x64 hi+lo
        int g = tid * 4 + r;
        int row = g >> 3, o = (g & 7) * 8;
        int os = o ^ ((row & 7) * 8);
        int gi = kbase + (j0 + row) * NE + ec * 64 + o;
        *(bf16x8*)(skh + row * 64 + os) = *(const bf16x8*)(kh + gi);
        *(bf16x8*)(skl + row * 64 + os) = *(const bf16x8*)(kl + gi);
      }
      __syncthreads();
#pragma unroll
      for (int ks = 0; ks < 4; ++ks) {
        int o = ks * 16 + lh * 8;
        int irow = mhalf * 32 + l31;
        int oq = o ^ ((irow & 7) * 8);
        bf16x8 aqh = *(const bf16x8*)(sqh + irow * 64 + oq);
        bf16x8 aql = *(const bf16x8*)(sql + irow * 64 + oq);
#pragma unroll
        for (int nt = 0; nt < 2; ++nt) {
          int jrow = npair * 64 + nt * 32 + l31;
          int ok = o ^ ((jrow & 7) * 8);
          bf16x8 bkh = *(const bf16x8*)(skh + jrow * 64 + ok);
          bf16x8 bkl = *(const bf16x8*)(skl + jrow * 64 + ok);
          S[nt] = mfma16(aqh, bkh, S[nt]);
          S[nt] = mfma16(aqh, bkl, S[nt]);
          S[nt] = mfma16(aql, bkh, S[nt]);
        }
      }
    }

    // ---- Phase B: online softmax ----
    float mr[16];
#pragma unroll
    for (int r = 0; r < 16; ++r) mr[r] = fmaxf(S[0][r], S[1][r]);
#pragma unroll
    for (int d = 1; d < 32; d <<= 1)
#pragma unroll
      for (int r = 0; r < 16; ++r)
        mr[r] = fmaxf(mr[r], __shfl_xor(mr[r], d, 64));
    if (l31 == 0) {
#pragma unroll
      for (int r = 0; r < 16; ++r) {
        int i = mhalf * 32 + (r & 3) + 8 * (r >> 2) + 4 * lh;
        s_red[i * 2 + npair] = mr[r];
      }
    }
    __syncthreads();
    if (tid < 64) {
      float mc = fmaxf(s_red[tid * 2], s_red[tid * 2 + 1]);
      float mn = fmaxf(s_m[tid], mc);
      s_alpha[tid] = __expf(s_m[tid] - mn);
      s_m[tid] = mn;
    }
    __syncthreads();
    float sr[16];
#pragma unroll
    for (int r = 0; r < 16; ++r) {
      int i = mhalf * 32 + (r & 3) + 8 * (r >> 2) + 4 * lh;
      float m = s_m[i];
      float p0 = __expf(S[0][r] - m);
      float p1 = __expf(S[1][r] - m);
      bf16 b0 = (bf16)p0, b1 = (bf16)p1;
      sP[i * 136 + npair * 64 + l31] = b0;
      sP[i * 136 + npair * 64 + 32 + l31] = b1;
      sr[r] = (float)b0 + (float)b1;   // sum what PV will actually use
    }
#pragma unroll
    for (int d = 1; d < 32; d <<= 1)
#pragma unroll
      for (int r = 0; r < 16; ++r) sr[r] += __shfl_xor(sr[r], d, 64);
    if (l31 == 0) {
#pragma unroll
      for (int r = 0; r < 16; ++r) {
        int i = mhalf * 32 + (r & 3) + 8 * (r >> 2) + 4 * lh;
        s_red[i * 2 + npair] = sr[r];
      }
    }
    // rescale O by alpha (O rows span both i-halves)
#pragma unroll
    for (int mt = 0; mt < 2; ++mt)
#pragma unroll
      for (int r = 0; r < 16; ++r) {
        float a = s_alpha[mt * 32 + (r & 3) + 8 * (r >> 2) + 4 * lh];
#pragma unroll
        for (int nt = 0; nt < 4; ++nt) O[mt][nt][r] *= a;
      }
    __syncthreads();
    if (tid < 64)
      s_l[tid] = s_l[tid] * s_alpha[tid] + s_red[tid * 2] + s_red[tid * 2 + 1];

    // ---- Phase C: O += P.v^T, v staged [512 e][stride 40] ----
    for (int jc = 0; jc < 4; ++jc) {
      __syncthreads();
#pragma unroll
      for (int r = 0; r < 8; ++r) {
        int g = r * 256 + tid;
        int row = g >> 2, o = (g & 3) * 8;
        int gi = vbase + row * NN + j0 + jc * 32 + o;
        *(bf16x8*)(svt + row * 40 + o) = *(const bf16x8*)(vt + gi);
      }
      __syncthreads();
#pragma unroll
      for (int ks = 0; ks < 2; ++ks) {
        bf16x8 ap[2];
#pragma unroll
        for (int mt = 0; mt < 2; ++mt) {
          int i = mt * 32 + l31;
          ap[mt] = *(const bf16x8*)(sP + i * 136 + jc * 32 + ks * 16 + lh * 8);
        }
#pragma unroll
        for (int nt = 0; nt < 4; ++nt) {
          int erow = wv * 128 + nt * 32 + l31;
          int o = ks * 16 + lh * 8;
          bf16x8 bv = *(const bf16x8*)(svt + erow * 40 + o);
#pragma unroll
          for (int mt = 0; mt < 2; ++mt)
            O[mt][nt] = mfma16(ap[mt], bv, O[mt][nt]);
        }
      }
    }
  }

  // ---- epilogue: out[b,e,i] = O[i,e]/l[i] + v[b,e,i] ----
  __syncthreads();
  if (tid < 64) s_alpha[tid] = 1.0f / s_l[tid];
  __syncthreads();
#pragma unroll
  for (int mt = 0; mt < 2; ++mt) {
#pragma unroll
    for (int nt = 0; nt < 4; ++nt) {
      int e = wv * 128 + nt * 32 + l31;
      int obase = (b * NE + e) * NN + i0;
#pragma unroll
      for (int g = 0; g < 4; ++g) {
        int ib = mt * 32 + g * 8 + 4 * lh;
        f32x4 rl = *(const f32x4*)(s_alpha + ib);
        bf16x4 v4 = *(const bf16x4*)(vt + vbase + e * NN + i0 + ib);
        f32x4 res;
#pragma unroll
        for (int j = 0; j < 4; ++j)
          res[j] = O[mt][nt][g * 4 + j] * rl[j] + (float)v4[j];
        *(f32x4*)(out + obase + ib) = res;
      }
    }
  }
}

// ---------------- launch ----------------
extern "C" void kernel_launch(void* const* d_in, const int* in_sizes, int n_in,
                              void* d_out, int out_size, void* d_ws, size_t ws_size,
                              hipStream_t stream) {
  const float* feat = (const float*)d_in[0];
  const float* Wq = (const float*)d_in[1];
  const float* bq = (const float*)d_in[2];
  const float* Wk = (const float*)d_in[3];
  const float* bk = (const float*)d_in[4];
  const float* Wv = (const float*)d_in[5];
  const float* bv = (const float*)d_in[6];
  float* out = (float*)d_out;

  char* ws = (char*)d_ws;
  size_t off = 0;
  auto alloc = [&](size_t bytes) {
    void* p = ws + off;
    off += (bytes + 255) & ~(size_t)255;
    return p;
  };
  const size_t FP = (size_t)NB * HP * HP * NC;     // 5,120,000
  const size_t WP = (size_t)9 * NE * NC;           // 1,179,648
  const size_t QP = (size_t)NB * NN * NE;          // 9,437,184
  bf16* fph = (bf16*)alloc(FP * 2);
  bf16* fpl = (bf16*)alloc(FP * 2);
  bf16* wqh = (bf16*)alloc(WP * 2);
  bf16* wql = (bf16*)alloc(WP * 2);
  bf16* wkh = (bf16*)alloc(WP * 2);
  bf16* wkl = (bf16*)alloc(WP * 2);
  bf16* wvh = (bf16*)alloc(WP * 2);
  bf16* q_hi = (bf16*)alloc(QP * 2);
  bf16* q_lo = (bf16*)alloc(QP * 2);
  bf16* k_hi = (bf16*)alloc(QP * 2);
  bf16* k_lo = (bf16*)alloc(QP * 2);
  bf16* v_t  = (bf16*)alloc(QP * 2);

  pack_feat<<<dim3(FP / 256), dim3(256), 0, stream>>>(feat, fph, fpl);
  pack_w<<<dim3(WP / 256), dim3(256), 0, stream>>>(Wq, Wk, Wv, wqh, wql, wkh, wkl, wvh);

  conv3<true><<<dim3(8, 48), dim3(256), 0, stream>>>(
      fph, fpl, wqh, wql, bq, q_hi, q_lo, (bf16*)nullptr);
  conv3<true><<<dim3(8, 48), dim3(256), 0, stream>>>(
      fph, fpl, wkh, wkl, bk, k_hi, k_lo, (bf16*)nullptr);
  conv3<false><<<dim3(8, 48), dim3(256), 0, stream>>>(
      fph, fpl, wvh, (bf16*)nullptr, bv, (bf16*)nullptr, (bf16*)nullptr, v_t);

  attn<<<dim3(36, 8), dim3(256), 0, stream>>>(q_hi, q_lo, k_hi, k_lo, v_t, out);
}

// Round 3
// 845.569 us; speedup vs baseline: 1.6931x; 1.6931x over previous
//
#include <hip/hip_runtime.h>

// ConvSA: B=8, C=256, H=W=48 (N=2304), E=512.
// out[b,e,i] = sum_j softmax_j(q[:,i].k[:,j]) * v[e,j] + v[e,i]
// Numerics: all-fp16 inputs with fp32 MFMA accumulate. fp16 products are
// exact in fp32; conv err ~4e-4, q/k store rounding 2.8e-4 -> logit noise
// ~1.6e-2 rms -> absmax ~0.05 vs threshold 0.149. PV in fp16 ~1e-3.

typedef _Float16 f16;
typedef _Float16 f16x4 __attribute__((ext_vector_type(4)));
typedef _Float16 f16x8 __attribute__((ext_vector_type(8)));
typedef float    f32x4  __attribute__((ext_vector_type(4)));
typedef float    f32x16 __attribute__((ext_vector_type(16)));

__device__ __forceinline__ f32x16 mfma16(f16x8 a, f16x8 b, f32x16 c) {
  return __builtin_amdgcn_mfma_f32_32x32x16_f16(a, b, c, 0, 0, 0);
}

#define NB   8
#define NC   256
#define NH   48
#define NN   2304     // 48*48
#define NE   512
#define HP   50       // padded H/W

// ---------------- pack kernels ----------------

// feat NCHW fp32 -> zero-padded NHWC [b][50][50][256] fp16
__global__ void pack_feat(const float* __restrict__ x, f16* __restrict__ p) {
  int idx = blockIdx.x * 256 + threadIdx.x;       // 8*50*50*256
  int c  = idx & 255;
  int q  = idx >> 8;
  int xp = q % 50; int t = q / 50; int yp = t % 50; int b = t / 50;
  float v = 0.f;
  if (yp >= 1 && yp <= 48 && xp >= 1 && xp <= 48)
    v = x[((b * NC + c) * NH + (yp - 1)) * NH + (xp - 1)];
  p[idx] = (f16)v;
}

// W OIHW [512][256][3][3] fp32 -> [tap][e][c] fp16 for q,k,v
__global__ void pack_w(const float* __restrict__ wq, const float* __restrict__ wk,
                       const float* __restrict__ wv,
                       f16* __restrict__ oq, f16* __restrict__ ok,
                       f16* __restrict__ ov) {
  int idx = blockIdx.x * 256 + threadIdx.x;       // 9*512*256
  int c = idx & 255;
  int r = idx >> 8;
  int e = r & 511; int t = r >> 9;
  int src = (e * NC + c) * 9 + t;
  oq[idx] = (f16)wq[src];
  ok[idx] = (f16)wk[src];
  ov[idx] = (f16)wv[src];
}

// ---------------- implicit-GEMM conv3x3 (fp16) ----------------
// Block 256 thr; out tile 64 e x 384 pos; grid (8 e-tiles, 48 = b*6 strips).
// TR=false: out [b][n][e] (q,k); TR=true: out [b][e][n] (v).
template<bool TR>
__global__ __launch_bounds__(256, 2) void conv3(
    const f16* __restrict__ xh, const f16* __restrict__ wh,
    const float* __restrict__ bias, f16* __restrict__ o) {
  __shared__ __align__(16) f16 sx[12000];         // 10*50*24

  const int tid = threadIdx.x;
  const int lane = tid & 63, wvx = tid >> 6;
  const int l31 = lane & 31;
  const int koff = (lane >> 5) * 8;
  const int e0 = blockIdx.x * 64;
  const int by = blockIdx.y;
  const int b = by / 6, strip = by % 6;
  const int y0 = strip * 8;

  int pb[3];
#pragma unroll
  for (int nt = 0; nt < 3; ++nt) {
    int n = wvx * 96 + nt * 32 + l31;
    pb[nt] = (n / 48) * 50 + (n % 48);
  }

  f32x16 acc[2][3];
#pragma unroll
  for (int mt = 0; mt < 2; ++mt)
#pragma unroll
    for (int nt = 0; nt < 3; ++nt)
#pragma unroll
      for (int i = 0; i < 16; ++i) acc[mt][nt][i] = 0.f;

  for (int cc = 0; cc < 16; ++cc) {
    const int c0 = cc * 16;
    __syncthreads();
    for (int g = tid; g < 1000; g += 256) {
      int p = g >> 1, of = (g & 1) * 8;
      int row = p / 50, xx = p % 50;
      int gidx = ((b * HP + y0 + row) * HP + xx) * NC + c0 + of;
      *(f16x8*)(sx + p * 24 + of) = *(const f16x8*)(xh + gidx);
    }
    __syncthreads();
#pragma unroll
    for (int t = 0; t < 9; ++t) {
      const int dy = t / 3, dx = t % 3;
      const int dpo = (dy * 50 + dx) * 24 + koff;
      f16x8 bh[3];
#pragma unroll
      for (int nt = 0; nt < 3; ++nt)
        bh[nt] = *(const f16x8*)(sx + pb[nt] * 24 + dpo);
#pragma unroll
      for (int mt = 0; mt < 2; ++mt) {
        int widx = ((t * NE) + e0 + mt * 32 + l31) * NC + c0 + koff;
        f16x8 ah = *(const f16x8*)(wh + widx);
#pragma unroll
        for (int nt = 0; nt < 3; ++nt)
          acc[mt][nt] = mfma16(ah, bh[nt], acc[mt][nt]);
      }
    }
  }

  // epilogue: C/D layout col=lane&31, row=(r&3)+8*(r>>2)+4*(lane>>5)
  const int colh = (lane >> 5) * 4;
#pragma unroll
  for (int mt = 0; mt < 2; ++mt) {
#pragma unroll
    for (int nt = 0; nt < 3; ++nt) {
      int n = wvx * 96 + nt * 32 + l31;
      int pos = (y0 + n / 48) * 48 + (n % 48);
#pragma unroll
      for (int g = 0; g < 4; ++g) {
        int eb = e0 + mt * 32 + g * 8 + colh;
        f32x4 bs = *(const f32x4*)(bias + eb);
        if constexpr (TR) {
#pragma unroll
          for (int j = 0; j < 4; ++j)
            o[(b * NE + eb + j) * NN + pos] = (f16)(acc[mt][nt][g * 4 + j] + bs[j]);
        } else {
          f16x4 h4;
#pragma unroll
          for (int j = 0; j < 4; ++j)
            h4[j] = (f16)(acc[mt][nt][g * 4 + j] + bs[j]);
          *(f16x4*)(o + (b * NN + pos) * NE + eb) = h4;
        }
      }
    }
  }
}

// ---------------- flash attention (fp16) ----------------
// Block 256 thr (4 waves); grid 288 linear, b = id&7 (XCD swizzle: each XCD's
// L2 holds one batch's K+V), i-tile = id>>3 (64 rows). j-tile 128.
// Phase A: double-buffered q(8KB)/k(16KB) e-chunks, register prefetch, one
// barrier per chunk. Phase B: online softmax fp32, P->LDS fp16 [64][136].
// Phase C: PV, v staged [512 e][stride 40] fp16 with register prefetch.
__global__ __launch_bounds__(256, 1) void attn(
    const f16* __restrict__ qt, const f16* __restrict__ kt,
    const f16* __restrict__ vt, float* __restrict__ out) {
  __shared__ __align__(16) f16 sAB[24576];  // q0|q1|k0|k1 ; Phase C: sv aliases
  __shared__ __align__(16) f16 sP[64 * 136];
  __shared__ __align__(16) float s_m[64];
  __shared__ __align__(16) float s_l[64];
  __shared__ __align__(16) float s_alpha[64];
  __shared__ __align__(16) float s_red[128];
  f16* sv = sAB;                                  // [512 e][stride 40] = 20480 f16

  const int tid = threadIdx.x;
  const int lane = tid & 63, wvx = tid >> 6;
  const int l31 = lane & 31, lh = lane >> 5;
  const int mhalf = wvx >> 1, npair = wvx & 1;
  const int bid = blockIdx.x;
  const int b = bid & 7, i0 = (bid >> 3) * 64;

  const int qbase = (b * NN + i0) * NE;
  const int kbase = b * NN * NE;
  const int vbase = b * NE * NN;

  if (tid < 64) { s_m[tid] = -3.0e38f; s_l[tid] = 0.f; }

  f32x16 O[2][4];
#pragma unroll
  for (int mt = 0; mt < 2; ++mt)
#pragma unroll
    for (int nt = 0; nt < 4; ++nt)
#pragma unroll
      for (int i = 0; i < 16; ++i) O[mt][nt][i] = 0.f;

  const int qrow = tid >> 3, qraw = tid & 7;      // q/k staging coords
  for (int jt = 0; jt < 18; ++jt) {
    const int j0 = jt * 128;
    f32x16 S[2];
#pragma unroll
    for (int nt = 0; nt < 2; ++nt)
#pragma unroll
      for (int i = 0; i < 16; ++i) S[nt][i] = 0.f;

    f16x8 rq[2], rk[4];
    // ---- prologue: prefetch e-chunk 0 ----
#pragma unroll
    for (int r = 0; r < 2; ++r)
      rq[r] = *(const f16x8*)(qt + qbase + (qrow + r * 32) * NE + qraw * 8);
#pragma unroll
    for (int r = 0; r < 4; ++r)
      rk[r] = *(const f16x8*)(kt + kbase + (j0 + qrow + r * 32) * NE + qraw * 8);
    __syncthreads();                              // sv alias (prev Phase C) done
#pragma unroll
    for (int r = 0; r < 2; ++r) {
      int row = qrow + r * 32;
      *(f16x8*)(sAB + row * 64 + ((qraw ^ (row & 7)) * 8)) = rq[r];
    }
#pragma unroll
    for (int r = 0; r < 4; ++r) {
      int row = qrow + r * 32;
      *(f16x8*)(sAB + 8192 + row * 64 + ((qraw ^ (row & 7)) * 8)) = rk[r];
    }

    // ---- Phase A: S = q.k^T, 8 e-chunks of 64, double-buffered ----
    for (int ec = 0; ec < 8; ++ec) {
      __syncthreads();
      const bool pf = (ec < 7);
      if (pf) {
#pragma unroll
        for (int r = 0; r < 2; ++r)
          rq[r] = *(const f16x8*)(qt + qbase + (qrow + r * 32) * NE + (ec + 1) * 64 + qraw * 8);
#pragma unroll
        for (int r = 0; r < 4; ++r)
          rk[r] = *(const f16x8*)(kt + kbase + (j0 + qrow + r * 32) * NE + (ec + 1) * 64 + qraw * 8);
      }
      const int qcur = (ec & 1) * 4096;
      const int kcur = 8192 + (ec & 1) * 8192;
      const int irow = mhalf * 32 + l31;
#pragma unroll
      for (int ks = 0; ks < 4; ++ks) {
        f16x8 aq = *(const f16x8*)(sAB + qcur + irow * 64 + (((ks * 2 + lh) ^ (irow & 7)) * 8));
#pragma unroll
        for (int nt = 0; nt < 2; ++nt) {
          int jrow = npair * 64 + nt * 32 + l31;
          f16x8 bk = *(const f16x8*)(sAB + kcur + jrow * 64 + (((ks * 2 + lh) ^ (jrow & 7)) * 8));
          S[nt] = mfma16(aq, bk, S[nt]);
        }
      }
      if (pf) {
        const int qn = ((ec + 1) & 1) * 4096;
        const int kn = 8192 + ((ec + 1) & 1) * 8192;
#pragma unroll
        for (int r = 0; r < 2; ++r) {
          int row = qrow + r * 32;
          *(f16x8*)(sAB + qn + row * 64 + ((qraw ^ (row & 7)) * 8)) = rq[r];
        }
#pragma unroll
        for (int r = 0; r < 4; ++r) {
          int row = qrow + r * 32;
          *(f16x8*)(sAB + kn + row * 64 + ((qraw ^ (row & 7)) * 8)) = rk[r];
        }
      }
    }

    // ---- Phase B: online softmax ----
    float mr[16];
#pragma unroll
    for (int r = 0; r < 16; ++r) mr[r] = fmaxf(S[0][r], S[1][r]);
#pragma unroll
    for (int d = 1; d < 32; d <<= 1)
#pragma unroll
      for (int r = 0; r < 16; ++r)
        mr[r] = fmaxf(mr[r], __shfl_xor(mr[r], d, 64));
    if (l31 == 0) {
#pragma unroll
      for (int r = 0; r < 16; ++r) {
        int i = mhalf * 32 + (r & 3) + 8 * (r >> 2) + 4 * lh;
        s_red[i * 2 + npair] = mr[r];
      }
    }
    __syncthreads();
    if (tid < 64) {
      float mc = fmaxf(s_red[tid * 2], s_red[tid * 2 + 1]);
      float mn = fmaxf(s_m[tid], mc);
      s_alpha[tid] = __expf(s_m[tid] - mn);
      s_m[tid] = mn;
    }
    __syncthreads();
    float sr[16];
#pragma unroll
    for (int r = 0; r < 16; ++r) {
      int i = mhalf * 32 + (r & 3) + 8 * (r >> 2) + 4 * lh;
      float m = s_m[i];
      float p0 = __expf(S[0][r] - m);
      float p1 = __expf(S[1][r] - m);
      f16 b0 = (f16)p0, b1 = (f16)p1;
      sP[i * 136 + npair * 64 + l31] = b0;
      sP[i * 136 + npair * 64 + 32 + l31] = b1;
      sr[r] = (float)b0 + (float)b1;              // sum what PV will use
    }
#pragma unroll
    for (int d = 1; d < 32; d <<= 1)
#pragma unroll
      for (int r = 0; r < 16; ++r) sr[r] += __shfl_xor(sr[r], d, 64);
    if (l31 == 0) {
#pragma unroll
      for (int r = 0; r < 16; ++r) {
        int i = mhalf * 32 + (r & 3) + 8 * (r >> 2) + 4 * lh;
        s_red[i * 2 + npair] = sr[r];
      }
    }
#pragma unroll
    for (int mt = 0; mt < 2; ++mt)
#pragma unroll
      for (int r = 0; r < 16; ++r) {
        float a = s_alpha[mt * 32 + (r & 3) + 8 * (r >> 2) + 4 * lh];
#pragma unroll
        for (int nt = 0; nt < 4; ++nt) O[mt][nt][r] *= a;
      }
    __syncthreads();
    if (tid < 64)
      s_l[tid] = s_l[tid] * s_alpha[tid] + s_red[tid * 2] + s_red[tid * 2 + 1];

    // ---- Phase C: O += P.v^T, v staged [512 e][stride 40] ----
    const int vrow = tid >> 2, vof = (tid & 3) * 8;
    for (int jc = 0; jc < 4; ++jc) {
      f16x8 rv[8];
#pragma unroll
      for (int r = 0; r < 8; ++r)
        rv[r] = *(const f16x8*)(vt + vbase + (vrow + r * 64) * NN + j0 + jc * 32 + vof);
      __syncthreads();                            // prev sv readers done
#pragma unroll
      for (int r = 0; r < 8; ++r)
        *(f16x8*)(sv + (vrow + r * 64) * 40 + vof) = rv[r];
      __syncthreads();
#pragma unroll
      for (int ks = 0; ks < 2; ++ks) {
        f16x8 ap[2];
#pragma unroll
        for (int mt = 0; mt < 2; ++mt) {
          int i = mt * 32 + l31;
          ap[mt] = *(const f16x8*)(sP + i * 136 + jc * 32 + ks * 16 + lh * 8);
        }
#pragma unroll
        for (int nt = 0; nt < 4; ++nt) {
          int erow = wvx * 128 + nt * 32 + l31;
          f16x8 bv = *(const f16x8*)(sv + erow * 40 + ks * 16 + lh * 8);
#pragma unroll
          for (int mt = 0; mt < 2; ++mt)
            O[mt][nt] = mfma16(ap[mt], bv, O[mt][nt]);
        }
      }
    }
  }

  // ---- epilogue: out[b,e,i] = O[i,e]/l[i] + v[b,e,i] ----
  __syncthreads();
  if (tid < 64) s_alpha[tid] = 1.0f / s_l[tid];
  __syncthreads();
#pragma unroll
  for (int mt = 0; mt < 2; ++mt) {
#pragma unroll
    for (int nt = 0; nt < 4; ++nt) {
      int e = wvx * 128 + nt * 32 + l31;
      int obase = (b * NE + e) * NN + i0;
#pragma unroll
      for (int g = 0; g < 4; ++g) {
        int ib = mt * 32 + g * 8 + 4 * lh;
        f32x4 rl = *(const f32x4*)(s_alpha + ib);
        f16x4 v4 = *(const f16x4*)(vt + vbase + e * NN + i0 + ib);
        f32x4 res;
#pragma unroll
        for (int j = 0; j < 4; ++j)
          res[j] = O[mt][nt][g * 4 + j] * rl[j] + (float)v4[j];
        *(f32x4*)(out + obase + ib) = res;
      }
    }
  }
}

// ---------------- launch ----------------
extern "C" void kernel_launch(void* const* d_in, const int* in_sizes, int n_in,
                              void* d_out, int out_size, void* d_ws, size_t ws_size,
                              hipStream_t stream) {
  const float* feat = (const float*)d_in[0];
  const float* Wq = (const float*)d_in[1];
  const float* bq = (const float*)d_in[2];
  const float* Wk = (const float*)d_in[3];
  const float* bk = (const float*)d_in[4];
  const float* Wv = (const float*)d_in[5];
  const float* bv = (const float*)d_in[6];
  float* out = (float*)d_out;

  char* ws = (char*)d_ws;
  size_t off = 0;
  auto alloc = [&](size_t bytes) {
    void* p = ws + off;
    off += (bytes + 255) & ~(size_t)255;
    return p;
  };
  const size_t FP = (size_t)NB * HP * HP * NC;     // 5,120,000
  const size_t WP = (size_t)9 * NE * NC;           // 1,179,648
  const size_t QP = (size_t)NB * NN * NE;          // 9,437,184
  f16* fp  = (f16*)alloc(FP * 2);
  f16* wq  = (f16*)alloc(WP * 2);
  f16* wk  = (f16*)alloc(WP * 2);
  f16* wv  = (f16*)alloc(WP * 2);
  f16* q_t = (f16*)alloc(QP * 2);
  f16* k_t = (f16*)alloc(QP * 2);
  f16* v_t = (f16*)alloc(QP * 2);

  pack_feat<<<dim3(FP / 256), dim3(256), 0, stream>>>(feat, fp);
  pack_w<<<dim3(WP / 256), dim3(256), 0, stream>>>(Wq, Wk, Wv, wq, wk, wv);

  conv3<false><<<dim3(8, 48), dim3(256), 0, stream>>>(fp, wq, bq, q_t);
  conv3<false><<<dim3(8, 48), dim3(256), 0, stream>>>(fp, wk, bk, k_t);
  conv3<true><<<dim3(8, 48), dim3(256), 0, stream>>>(fp, wv, bv, v_t);

  attn<<<dim3(288), dim3(256), 0, stream>>>(q_t, k_t, v_t, out);
}

// Round 4
// 806.462 us; speedup vs baseline: 1.7752x; 1.0485x over previous
//
#include <hip/hip_runtime.h>

// ConvSA: B=8, C=256, H=W=48 (N=2304), E=512.
// out[b,e,i] = sum_j softmax_j(q[:,i].k[:,j]) * v[e,j] + v[e,i]
// All-fp16 operands, fp32 MFMA accumulate. Flash attention with split-j x2
// (two j-halves of 1152 in separate blocks; fp16 partial O + m,l combined by
// a small epilogue kernel). V consumed directly from global as MFMA B-frags
// (XCD-L2 resident: b = blockIdx&7 matches XCD round-robin).

typedef _Float16 f16;
typedef _Float16 f16x4 __attribute__((ext_vector_type(4)));
typedef _Float16 f16x8 __attribute__((ext_vector_type(8)));
typedef float    f32x4  __attribute__((ext_vector_type(4)));
typedef float    f32x16 __attribute__((ext_vector_type(16)));

__device__ __forceinline__ f32x16 mfma16(f16x8 a, f16x8 b, f32x16 c) {
  return __builtin_amdgcn_mfma_f32_32x32x16_f16(a, b, c, 0, 0, 0);
}

#define NB   8
#define NC   256
#define NH   48
#define NN   2304     // 48*48
#define NE   512
#define HP   50       // padded H/W

// ---------------- pack kernels ----------------

// feat NCHW fp32 -> zero-padded NHWC [b][50][50][256] fp16
__global__ void pack_feat(const float* __restrict__ x, f16* __restrict__ p) {
  int idx = blockIdx.x * 256 + threadIdx.x;       // 8*50*50*256
  int c  = idx & 255;
  int q  = idx >> 8;
  int xp = q % 50; int t = q / 50; int yp = t % 50; int b = t / 50;
  float v = 0.f;
  if (yp >= 1 && yp <= 48 && xp >= 1 && xp <= 48)
    v = x[((b * NC + c) * NH + (yp - 1)) * NH + (xp - 1)];
  p[idx] = (f16)v;
}

// W OIHW [512][256][3][3] fp32 -> [tap][e][c] fp16 for q,k,v
__global__ void pack_w(const float* __restrict__ wq, const float* __restrict__ wk,
                       const float* __restrict__ wv,
                       f16* __restrict__ oq, f16* __restrict__ ok,
                       f16* __restrict__ ov) {
  int idx = blockIdx.x * 256 + threadIdx.x;       // 9*512*256
  int c = idx & 255;
  int r = idx >> 8;
  int e = r & 511; int t = r >> 9;
  int src = (e * NC + c) * 9 + t;
  oq[idx] = (f16)wq[src];
  ok[idx] = (f16)wk[src];
  ov[idx] = (f16)wv[src];
}

// ---------------- implicit-GEMM conv3x3 (fp16) ----------------
// Block 256 thr; out tile 32 e x 384 pos; grid (16 e-tiles, 48 = b*6 strips).
// acc 48 VGPR -> launch_bounds(256,4): 4 blocks/CU capacity, grid 768.
// TR=false: out [b][n][e] (q,k); TR=true: out [b][e][n] (v).
template<bool TR>
__global__ __launch_bounds__(256, 4) void conv3(
    const f16* __restrict__ xh, const f16* __restrict__ wh,
    const float* __restrict__ bias, f16* __restrict__ o) {
  __shared__ __align__(16) f16 sx[12000];         // 10*50*24

  const int tid = threadIdx.x;
  const int lane = tid & 63, wvx = tid >> 6;
  const int l31 = lane & 31;
  const int koff = (lane >> 5) * 8;
  const int e0 = blockIdx.x * 32;
  const int by = blockIdx.y;
  const int b = by / 6, strip = by % 6;
  const int y0 = strip * 8;

  int pb[3];
#pragma unroll
  for (int nt = 0; nt < 3; ++nt) {
    int n = wvx * 96 + nt * 32 + l31;
    pb[nt] = (n / 48) * 50 + (n % 48);
  }

  f32x16 acc[3];
#pragma unroll
  for (int nt = 0; nt < 3; ++nt)
#pragma unroll
    for (int i = 0; i < 16; ++i) acc[nt][i] = 0.f;

  for (int cc = 0; cc < 16; ++cc) {
    const int c0 = cc * 16;
    __syncthreads();
    for (int g = tid; g < 1000; g += 256) {
      int p = g >> 1, of = (g & 1) * 8;
      int row = p / 50, xx = p % 50;
      int gidx = ((b * HP + y0 + row) * HP + xx) * NC + c0 + of;
      *(f16x8*)(sx + p * 24 + of) = *(const f16x8*)(xh + gidx);
    }
    __syncthreads();
#pragma unroll
    for (int t = 0; t < 9; ++t) {
      const int dy = t / 3, dx = t % 3;
      const int dpo = (dy * 50 + dx) * 24 + koff;
      f16x8 bh[3];
#pragma unroll
      for (int nt = 0; nt < 3; ++nt)
        bh[nt] = *(const f16x8*)(sx + pb[nt] * 24 + dpo);
      int widx = ((t * NE) + e0 + l31) * NC + c0 + koff;
      f16x8 ah = *(const f16x8*)(wh + widx);
#pragma unroll
      for (int nt = 0; nt < 3; ++nt)
        acc[nt] = mfma16(ah, bh[nt], acc[nt]);
    }
  }

  // epilogue: C/D layout col=lane&31 (=pos), row=(r&3)+8*(r>>2)+4*(lane>>5) (=e)
  const int colh = (lane >> 5) * 4;
#pragma unroll
  for (int nt = 0; nt < 3; ++nt) {
    int n = wvx * 96 + nt * 32 + l31;
    int pos = (y0 + n / 48) * 48 + (n % 48);
#pragma unroll
    for (int g = 0; g < 4; ++g) {
      int eb = e0 + g * 8 + colh;
      f32x4 bs = *(const f32x4*)(bias + eb);
      if constexpr (TR) {
#pragma unroll
        for (int j = 0; j < 4; ++j)
          o[(b * NE + eb + j) * NN + pos] = (f16)(acc[nt][g * 4 + j] + bs[j]);
      } else {
        f16x4 h4;
#pragma unroll
        for (int j = 0; j < 4; ++j)
          h4[j] = (f16)(acc[nt][g * 4 + j] + bs[j]);
        *(f16x4*)(o + (b * NN + pos) * NE + eb) = h4;
      }
    }
  }
}

// ---------------- flash attention (fp16, split-j x2) ----------------
// Grid 576: b = bid&7 (XCD swizzle), jh = (bid>>3)&1 (j-half), i-tile = bid>>4.
// Per block: 64 i-rows x 1152 j (9 j-tiles of 128).
// Phase A: double-buffered q(8KB)/k(16KB) e-chunks in LDS, register prefetch.
// Phase B: online softmax fp32, P->LDS fp16 [64][136]; 3 barriers.
// Phase C: PV with V B-frags straight from global (L2), zero barriers.
// Output: partial O (fp16, unnormalized) + m,l to workspace; combine() reduces.
__global__ __launch_bounds__(256, 2) void attn(
    const f16* __restrict__ qt, const f16* __restrict__ kt,
    const f16* __restrict__ vt, f16* __restrict__ po,
    float* __restrict__ pm, float* __restrict__ pl) {
  __shared__ __align__(16) f16 sAB[24576];  // q dbuf 2x4096 | k dbuf 2x8192
  __shared__ __align__(16) f16 sP[64 * 136];
  __shared__ __align__(16) float s_m[64];
  __shared__ __align__(16) float s_l[64];
  __shared__ __align__(16) float s_alpha[64];
  __shared__ __align__(16) float s_red[128];

  const int tid = threadIdx.x;
  const int lane = tid & 63, wvx = tid >> 6;
  const int l31 = lane & 31, lh = lane >> 5;
  const int mhalf = wvx >> 1, npair = wvx & 1;
  const int bid = blockIdx.x;
  const int b = bid & 7;
  const int jh = (bid >> 3) & 1;
  const int i0 = (bid >> 4) * 64;

  const int qbase = (b * NN + i0) * NE;
  const int kbase = b * NN * NE;
  const int vbase = b * NE * NN;

  if (tid < 64) { s_m[tid] = -3.0e38f; s_l[tid] = 0.f; }

  f32x16 O[2][4];
#pragma unroll
  for (int mt = 0; mt < 2; ++mt)
#pragma unroll
    for (int nt = 0; nt < 4; ++nt)
#pragma unroll
      for (int i = 0; i < 16; ++i) O[mt][nt][i] = 0.f;

  const int qrow = tid >> 3, qraw = tid & 7;      // q/k staging coords
  for (int jt = 0; jt < 9; ++jt) {
    const int j0 = jh * 1152 + jt * 128;
    f32x16 S[2];
#pragma unroll
    for (int nt = 0; nt < 2; ++nt)
#pragma unroll
      for (int i = 0; i < 16; ++i) S[nt][i] = 0.f;

    f16x8 rq[2], rk[4];
    // ---- prologue: prefetch e-chunk 0 into buffer 0 ----
#pragma unroll
    for (int r = 0; r < 2; ++r)
      rq[r] = *(const f16x8*)(qt + qbase + (qrow + r * 32) * NE + qraw * 8);
#pragma unroll
    for (int r = 0; r < 4; ++r)
      rk[r] = *(const f16x8*)(kt + kbase + (j0 + qrow + r * 32) * NE + qraw * 8);
#pragma unroll
    for (int r = 0; r < 2; ++r) {
      int row = qrow + r * 32;
      *(f16x8*)(sAB + row * 64 + ((qraw ^ (row & 7)) * 8)) = rq[r];
    }
#pragma unroll
    for (int r = 0; r < 4; ++r) {
      int row = qrow + r * 32;
      *(f16x8*)(sAB + 8192 + row * 64 + ((qraw ^ (row & 7)) * 8)) = rk[r];
    }

    // ---- Phase A: S = q.k^T, 8 e-chunks of 64, double-buffered ----
    for (int ec = 0; ec < 8; ++ec) {
      __syncthreads();
      const bool pf = (ec < 7);
      if (pf) {
#pragma unroll
        for (int r = 0; r < 2; ++r)
          rq[r] = *(const f16x8*)(qt + qbase + (qrow + r * 32) * NE + (ec + 1) * 64 + qraw * 8);
#pragma unroll
        for (int r = 0; r < 4; ++r)
          rk[r] = *(const f16x8*)(kt + kbase + (j0 + qrow + r * 32) * NE + (ec + 1) * 64 + qraw * 8);
      }
      const int qcur = (ec & 1) * 4096;
      const int kcur = 8192 + (ec & 1) * 8192;
      const int irow = mhalf * 32 + l31;
#pragma unroll
      for (int ks = 0; ks < 4; ++ks) {
        f16x8 aq = *(const f16x8*)(sAB + qcur + irow * 64 + (((ks * 2 + lh) ^ (irow & 7)) * 8));
#pragma unroll
        for (int nt = 0; nt < 2; ++nt) {
          int jrow = npair * 64 + nt * 32 + l31;
          f16x8 bk = *(const f16x8*)(sAB + kcur + jrow * 64 + (((ks * 2 + lh) ^ (jrow & 7)) * 8));
          S[nt] = mfma16(aq, bk, S[nt]);
        }
      }
      if (pf) {
        const int qn = ((ec + 1) & 1) * 4096;
        const int kn = 8192 + ((ec + 1) & 1) * 8192;
#pragma unroll
        for (int r = 0; r < 2; ++r) {
          int row = qrow + r * 32;
          *(f16x8*)(sAB + qn + row * 64 + ((qraw ^ (row & 7)) * 8)) = rq[r];
        }
#pragma unroll
        for (int r = 0; r < 4; ++r) {
          int row = qrow + r * 32;
          *(f16x8*)(sAB + kn + row * 64 + ((qraw ^ (row & 7)) * 8)) = rk[r];
        }
      }
    }

    // ---- Phase B: online softmax (3 barriers) ----
    float mr[16];
#pragma unroll
    for (int r = 0; r < 16; ++r) mr[r] = fmaxf(S[0][r], S[1][r]);
#pragma unroll
    for (int d = 1; d < 32; d <<= 1)
#pragma unroll
      for (int r = 0; r < 16; ++r)
        mr[r] = fmaxf(mr[r], __shfl_xor(mr[r], d, 64));
    if (l31 == 0) {
#pragma unroll
      for (int r = 0; r < 16; ++r) {
        int i = mhalf * 32 + (r & 3) + 8 * (r >> 2) + 4 * lh;
        s_red[i * 2 + npair] = mr[r];
      }
    }
    __syncthreads();
    if (tid < 64) {
      float mc = fmaxf(s_red[tid * 2], s_red[tid * 2 + 1]);
      float mn = fmaxf(s_m[tid], mc);
      s_alpha[tid] = __expf(s_m[tid] - mn);
      s_m[tid] = mn;
    }
    __syncthreads();
    float sr[16];
#pragma unroll
    for (int r = 0; r < 16; ++r) {
      int i = mhalf * 32 + (r & 3) + 8 * (r >> 2) + 4 * lh;
      float m = s_m[i];
      float p0 = __expf(S[0][r] - m);
      float p1 = __expf(S[1][r] - m);
      f16 b0 = (f16)p0, b1 = (f16)p1;
      sP[i * 136 + npair * 64 + l31] = b0;
      sP[i * 136 + npair * 64 + 32 + l31] = b1;
      sr[r] = (float)b0 + (float)b1;              // sum what PV will use
    }
#pragma unroll
    for (int d = 1; d < 32; d <<= 1)
#pragma unroll
      for (int r = 0; r < 16; ++r) sr[r] += __shfl_xor(sr[r], d, 64);
    if (l31 == 0) {
#pragma unroll
      for (int r = 0; r < 16; ++r) {
        int i = mhalf * 32 + (r & 3) + 8 * (r >> 2) + 4 * lh;
        s_red[i * 2 + npair] = sr[r];
      }
    }
#pragma unroll
    for (int mt = 0; mt < 2; ++mt)
#pragma unroll
      for (int r = 0; r < 16; ++r) {
        float a = s_alpha[mt * 32 + (r & 3) + 8 * (r >> 2) + 4 * lh];
#pragma unroll
        for (int nt = 0; nt < 4; ++nt) O[mt][nt][r] *= a;
      }
    __syncthreads();
    if (tid < 64)
      s_l[tid] = s_l[tid] * s_alpha[tid] + s_red[tid * 2] + s_red[tid * 2 + 1];

    // ---- Phase C: O += P.V^T, V B-frags direct from global (no barriers) ----
#pragma unroll
    for (int ks = 0; ks < 8; ++ks) {
      f16x8 ap[2];
#pragma unroll
      for (int mt = 0; mt < 2; ++mt)
        ap[mt] = *(const f16x8*)(sP + (mt * 32 + l31) * 136 + ks * 16 + lh * 8);
      f16x8 bv[4];
#pragma unroll
      for (int nt = 0; nt < 4; ++nt) {
        int erow = wvx * 128 + nt * 32 + l31;
        bv[nt] = *(const f16x8*)(vt + vbase + erow * NN + j0 + ks * 16 + lh * 8);
      }
#pragma unroll
      for (int nt = 0; nt < 4; ++nt)
#pragma unroll
        for (int mt = 0; mt < 2; ++mt)
          O[mt][nt] = mfma16(ap[mt], bv[nt], O[mt][nt]);
    }
  }

  // ---- epilogue: store partial O (fp16, unnormalized) + m,l ----
  const size_t pobase = ((size_t)(jh * NB + b) * NE) * NN;
  if (tid < 64) {
    pm[(jh * NB + b) * NN + i0 + tid] = s_m[tid];
    pl[(jh * NB + b) * NN + i0 + tid] = s_l[tid];
  }
#pragma unroll
  for (int mt = 0; mt < 2; ++mt) {
#pragma unroll
    for (int nt = 0; nt < 4; ++nt) {
      int e = wvx * 128 + nt * 32 + l31;
#pragma unroll
      for (int g = 0; g < 4; ++g) {
        int ib = mt * 32 + g * 8 + 4 * lh;
        f16x4 h4;
#pragma unroll
        for (int j = 0; j < 4; ++j)
          h4[j] = (f16)O[mt][nt][g * 4 + j];
        *(f16x4*)(po + pobase + (size_t)e * NN + i0 + ib) = h4;
      }
    }
  }
}

// ---------------- combine: merge 2 j-halves, divide, add v ----------------
__global__ void combine(const f16* __restrict__ po, const float* __restrict__ pm,
                        const float* __restrict__ pl, const f16* __restrict__ vt,
                        float* __restrict__ out) {
  int id = blockIdx.x * 256 + threadIdx.x;        // NB*NE*NN/4 = 2,359,296
  int base = id * 4;
  int i  = base % NN;
  int eb = base / NN;                             // b*NE + e
  int b  = eb >> 9;
  const size_t H = (size_t)NB * NE * NN;
  f32x4 m0 = *(const f32x4*)(pm + b * NN + i);
  f32x4 m1 = *(const f32x4*)(pm + NB * NN + b * NN + i);
  f32x4 l0 = *(const f32x4*)(pl + b * NN + i);
  f32x4 l1 = *(const f32x4*)(pl + NB * NN + b * NN + i);
  f16x4 a0 = *(const f16x4*)(po + (size_t)eb * NN + i);
  f16x4 a1 = *(const f16x4*)(po + H + (size_t)eb * NN + i);
  f16x4 vv = *(const f16x4*)(vt + (size_t)eb * NN + i);
  f32x4 res;
#pragma unroll
  for (int j = 0; j < 4; ++j) {
    float m = fmaxf(m0[j], m1[j]);
    float w0 = __expf(m0[j] - m), w1 = __expf(m1[j] - m);
    float l = w0 * l0[j] + w1 * l1[j];
    res[j] = (w0 * (float)a0[j] + w1 * (float)a1[j]) / l + (float)vv[j];
  }
  *(f32x4*)(out + (size_t)eb * NN + i) = res;
}

// ---------------- launch ----------------
extern "C" void kernel_launch(void* const* d_in, const int* in_sizes, int n_in,
                              void* d_out, int out_size, void* d_ws, size_t ws_size,
                              hipStream_t stream) {
  const float* feat = (const float*)d_in[0];
  const float* Wq = (const float*)d_in[1];
  const float* bq = (const float*)d_in[2];
  const float* Wk = (const float*)d_in[3];
  const float* bk = (const float*)d_in[4];
  const float* Wv = (const float*)d_in[5];
  const float* bv = (const float*)d_in[6];
  float* out = (float*)d_out;

  char* ws = (char*)d_ws;
  size_t off = 0;
  auto alloc = [&](size_t bytes) {
    void* p = ws + off;
    off += (bytes + 255) & ~(size_t)255;
    return p;
  };
  const size_t FP = (size_t)NB * HP * HP * NC;     // 5,120,000
  const size_t WP = (size_t)9 * NE * NC;           // 1,179,648
  const size_t QP = (size_t)NB * NN * NE;          // 9,437,184
  f16* fp  = (f16*)alloc(FP * 2);
  f16* wq  = (f16*)alloc(WP * 2);
  f16* wk  = (f16*)alloc(WP * 2);
  f16* wv  = (f16*)alloc(WP * 2);
  f16* q_t = (f16*)alloc(QP * 2);
  f16* k_t = (f16*)alloc(QP * 2);
  f16* v_t = (f16*)alloc(QP * 2);
  f16* po  = (f16*)alloc(2 * QP * 2);              // 37.7 MB partial O
  float* pm = (float*)alloc(2 * (size_t)NB * NN * 4);
  float* pl = (float*)alloc(2 * (size_t)NB * NN * 4);

  pack_feat<<<dim3(FP / 256), dim3(256), 0, stream>>>(feat, fp);
  pack_w<<<dim3(WP / 256), dim3(256), 0, stream>>>(Wq, Wk, Wv, wq, wk, wv);

  conv3<false><<<dim3(16, 48), dim3(256), 0, stream>>>(fp, wq, bq, q_t);
  conv3<false><<<dim3(16, 48), dim3(256), 0, stream>>>(fp, wk, bk, k_t);
  conv3<true><<<dim3(16, 48), dim3(256), 0, stream>>>(fp, wv, bv, v_t);

  attn<<<dim3(576), dim3(256), 0, stream>>>(q_t, k_t, v_t, po, pm, pl);
  combine<<<dim3((NB * NE * NN / 4) / 256), dim3(256), 0, stream>>>(po, pm, pl, v_t, out);
}

// Round 5
// 742.590 us; speedup vs baseline: 1.9278x; 1.0860x over previous
//
#include <hip/hip_runtime.h>

// ConvSA: B=8, C=256, H=W=48 (N=2304), E=512.
// out[b,e,i] = sum_j softmax_j(q[:,i].k[:,j]) * v[e,j] + v[e,i]
// All-fp16 operands, fp32 MFMA accumulate. Fused qkv conv (shared X tile).
// Flash attention, split-j x2, XCD-swizzled b; V staged per-wave in LDS
// (wave-private region -> no barriers in PV phase); combine() merges halves.

typedef _Float16 f16;
typedef _Float16 f16x4 __attribute__((ext_vector_type(4)));
typedef _Float16 f16x8 __attribute__((ext_vector_type(8)));
typedef float    f32x4  __attribute__((ext_vector_type(4)));
typedef float    f32x16 __attribute__((ext_vector_type(16)));

__device__ __forceinline__ f32x16 mfma16(f16x8 a, f16x8 b, f32x16 c) {
  return __builtin_amdgcn_mfma_f32_32x32x16_f16(a, b, c, 0, 0, 0);
}

#define NB   8
#define NC   256
#define NH   48
#define NN   2304     // 48*48
#define NE   512
#define HP   50       // padded H/W

// ---------------- pack kernels ----------------

// feat NCHW fp32 -> zero-padded NHWC [b][50][50][256] fp16
__global__ void pack_feat(const float* __restrict__ x, f16* __restrict__ p) {
  int idx = blockIdx.x * 256 + threadIdx.x;       // 8*50*50*256
  int c  = idx & 255;
  int q  = idx >> 8;
  int xp = q % 50; int t = q / 50; int yp = t % 50; int b = t / 50;
  float v = 0.f;
  if (yp >= 1 && yp <= 48 && xp >= 1 && xp <= 48)
    v = x[((b * NC + c) * NH + (yp - 1)) * NH + (xp - 1)];
  p[idx] = (f16)v;
}

// W OIHW [512][256][3][3] fp32 -> [tap][e][c] fp16 for q,k,v
__global__ void pack_w(const float* __restrict__ wq, const float* __restrict__ wk,
                       const float* __restrict__ wv,
                       f16* __restrict__ oq, f16* __restrict__ ok,
                       f16* __restrict__ ov) {
  int idx = blockIdx.x * 256 + threadIdx.x;       // 9*512*256
  int c = idx & 255;
  int r = idx >> 8;
  int e = r & 511; int t = r >> 9;
  int src = (e * NC + c) * 9 + t;
  oq[idx] = (f16)wq[src];
  ok[idx] = (f16)wk[src];
  ov[idx] = (f16)wv[src];
}

// ---------------- fused implicit-GEMM conv3x3 for q,k,v ----------------
// Block 256 thr; out tile 32 e x 384 pos x {q,k,v}; grid (16 e-tiles, 48).
// One X-tile staging serves 3 convs (3x MFMA per staged byte).
// q,k -> [b][n][e]; v -> [b][e][n].
__global__ __launch_bounds__(256, 2) void conv3_qkv(
    const f16* __restrict__ xh,
    const f16* __restrict__ wq, const f16* __restrict__ wk,
    const f16* __restrict__ wv,
    const float* __restrict__ bq, const float* __restrict__ bk,
    const float* __restrict__ bv,
    f16* __restrict__ oq, f16* __restrict__ ok, f16* __restrict__ ov) {
  __shared__ __align__(16) f16 sx[12000];         // 10*50*24

  const int tid = threadIdx.x;
  const int lane = tid & 63, wvx = tid >> 6;
  const int l31 = lane & 31;
  const int koff = (lane >> 5) * 8;
  const int e0 = blockIdx.x * 32;
  const int by = blockIdx.y;
  const int b = by / 6, strip = by % 6;
  const int y0 = strip * 8;

  int pb[3];
#pragma unroll
  for (int nt = 0; nt < 3; ++nt) {
    int n = wvx * 96 + nt * 32 + l31;
    pb[nt] = (n / 48) * 50 + (n % 48);
  }

  f32x16 acc[3][3];                               // [qkv][nt]
#pragma unroll
  for (int f = 0; f < 3; ++f)
#pragma unroll
    for (int nt = 0; nt < 3; ++nt)
#pragma unroll
      for (int i = 0; i < 16; ++i) acc[f][nt][i] = 0.f;

  for (int cc = 0; cc < 16; ++cc) {
    const int c0 = cc * 16;
    __syncthreads();
    for (int g = tid; g < 1000; g += 256) {
      int p = g >> 1, of = (g & 1) * 8;
      int row = p / 50, xx = p % 50;
      int gidx = ((b * HP + y0 + row) * HP + xx) * NC + c0 + of;
      *(f16x8*)(sx + p * 24 + of) = *(const f16x8*)(xh + gidx);
    }
    __syncthreads();
#pragma unroll
    for (int t = 0; t < 9; ++t) {
      const int dy = t / 3, dx = t % 3;
      const int dpo = (dy * 50 + dx) * 24 + koff;
      f16x8 bh[3];
#pragma unroll
      for (int nt = 0; nt < 3; ++nt)
        bh[nt] = *(const f16x8*)(sx + pb[nt] * 24 + dpo);
      int widx = ((t * NE) + e0 + l31) * NC + c0 + koff;
      f16x8 aq = *(const f16x8*)(wq + widx);
      f16x8 ak = *(const f16x8*)(wk + widx);
      f16x8 av = *(const f16x8*)(wv + widx);
#pragma unroll
      for (int nt = 0; nt < 3; ++nt) {
        acc[0][nt] = mfma16(aq, bh[nt], acc[0][nt]);
        acc[1][nt] = mfma16(ak, bh[nt], acc[1][nt]);
        acc[2][nt] = mfma16(av, bh[nt], acc[2][nt]);
      }
    }
  }

  // epilogue: C/D layout col=lane&31 (=pos), row=(r&3)+8*(r>>2)+4*(lane>>5) (=e)
  const int colh = (lane >> 5) * 4;
#pragma unroll
  for (int nt = 0; nt < 3; ++nt) {
    int n = wvx * 96 + nt * 32 + l31;
    int pos = (y0 + n / 48) * 48 + (n % 48);
#pragma unroll
    for (int g = 0; g < 4; ++g) {
      int eb = e0 + g * 8 + colh;
      f32x4 sq = *(const f32x4*)(bq + eb);
      f32x4 sk = *(const f32x4*)(bk + eb);
      f32x4 sv = *(const f32x4*)(bv + eb);
      f16x4 hq, hk;
#pragma unroll
      for (int j = 0; j < 4; ++j) {
        hq[j] = (f16)(acc[0][nt][g * 4 + j] + sq[j]);
        hk[j] = (f16)(acc[1][nt][g * 4 + j] + sk[j]);
        ov[(b * NE + eb + j) * NN + pos] = (f16)(acc[2][nt][g * 4 + j] + sv[j]);
      }
      *(f16x4*)(oq + (b * NN + pos) * NE + eb) = hq;
      *(f16x4*)(ok + (b * NN + pos) * NE + eb) = hk;
    }
  }
}

// ---------------- flash attention (fp16, split-j x2) ----------------
// Grid 576: b = bid&7 (XCD swizzle), jh = (bid>>3)&1, i-tile = bid>>4 (64 rows).
// Phase A: double-buffered q(8KB)/k(16KB) e-chunks in LDS, register prefetch.
// Phase B: online softmax fp32, P->LDS fp16 [64][136]; 3 barriers.
// Phase C: PV; V staged per-wave into private LDS region (stride 40) -> no
//          barriers; register-dbuf global loads; jc0 prefetched in Phase B.
// Output: partial O (fp16, unnormalized) + m,l; combine() merges halves.
__global__ __launch_bounds__(256, 2) void attn(
    const f16* __restrict__ qt, const f16* __restrict__ kt,
    const f16* __restrict__ vt, f16* __restrict__ po,
    float* __restrict__ pm, float* __restrict__ pl) {
  __shared__ __align__(16) f16 sAB[24576];  // A: q dbuf 2x4096 | k dbuf 2x8192
                                            // C: per-wave V: wvx*5120, [128][40]
  __shared__ __align__(16) f16 sP[64 * 136];
  __shared__ __align__(16) float s_m[64];
  __shared__ __align__(16) float s_l[64];
  __shared__ __align__(16) float s_alpha[64];
  __shared__ __align__(16) float s_red[128];

  const int tid = threadIdx.x;
  const int lane = tid & 63, wvx = tid >> 6;
  const int l31 = lane & 31, lh = lane >> 5;
  const int mhalf = wvx >> 1, npair = wvx & 1;
  const int bid = blockIdx.x;
  const int b = bid & 7;
  const int jh = (bid >> 3) & 1;
  const int i0 = (bid >> 4) * 64;

  const int qbase = (b * NN + i0) * NE;
  const int kbase = b * NN * NE;
  const int vbase = b * NE * NN;
  f16* svw = sAB + wvx * 5120;                    // wave-private V region

  if (tid < 64) { s_m[tid] = -3.0e38f; s_l[tid] = 0.f; }

  f32x16 O[2][4];
#pragma unroll
  for (int mt = 0; mt < 2; ++mt)
#pragma unroll
    for (int nt = 0; nt < 4; ++nt)
#pragma unroll
      for (int i = 0; i < 16; ++i) O[mt][nt][i] = 0.f;

  const int qrow = tid >> 3, qraw = tid & 7;      // q/k staging coords
  for (int jt = 0; jt < 9; ++jt) {
    const int j0 = jh * 1152 + jt * 128;
    f32x16 S[2];
#pragma unroll
    for (int nt = 0; nt < 2; ++nt)
#pragma unroll
      for (int i = 0; i < 16; ++i) S[nt][i] = 0.f;

    f16x8 rq[2], rk[4];
    // prologue: prefetch e-chunk 0, then barrier (prev Phase C done), store.
#pragma unroll
    for (int r = 0; r < 2; ++r)
      rq[r] = *(const f16x8*)(qt + qbase + (qrow + r * 32) * NE + qraw * 8);
#pragma unroll
    for (int r = 0; r < 4; ++r)
      rk[r] = *(const f16x8*)(kt + kbase + (j0 + qrow + r * 32) * NE + qraw * 8);
    __syncthreads();
#pragma unroll
    for (int r = 0; r < 2; ++r) {
      int row = qrow + r * 32;
      *(f16x8*)(sAB + row * 64 + ((qraw ^ (row & 7)) * 8)) = rq[r];
    }
#pragma unroll
    for (int r = 0; r < 4; ++r) {
      int row = qrow + r * 32;
      *(f16x8*)(sAB + 8192 + row * 64 + ((qraw ^ (row & 7)) * 8)) = rk[r];
    }

    // ---- Phase A: S = q.k^T, 8 e-chunks of 64, double-buffered ----
    for (int ec = 0; ec < 8; ++ec) {
      __syncthreads();
      const bool pf = (ec < 7);
      if (pf) {
#pragma unroll
        for (int r = 0; r < 2; ++r)
          rq[r] = *(const f16x8*)(qt + qbase + (qrow + r * 32) * NE + (ec + 1) * 64 + qraw * 8);
#pragma unroll
        for (int r = 0; r < 4; ++r)
          rk[r] = *(const f16x8*)(kt + kbase + (j0 + qrow + r * 32) * NE + (ec + 1) * 64 + qraw * 8);
      }
      const int qcur = (ec & 1) * 4096;
      const int kcur = 8192 + (ec & 1) * 8192;
      const int irow = mhalf * 32 + l31;
#pragma unroll
      for (int ks = 0; ks < 4; ++ks) {
        f16x8 aq = *(const f16x8*)(sAB + qcur + irow * 64 + (((ks * 2 + lh) ^ (irow & 7)) * 8));
#pragma unroll
        for (int nt = 0; nt < 2; ++nt) {
          int jrow = npair * 64 + nt * 32 + l31;
          f16x8 bk = *(const f16x8*)(sAB + kcur + jrow * 64 + (((ks * 2 + lh) ^ (jrow & 7)) * 8));
          S[nt] = mfma16(aq, bk, S[nt]);
        }
      }
      if (pf) {
        const int qn = ((ec + 1) & 1) * 4096;
        const int kn = 8192 + ((ec + 1) & 1) * 8192;
#pragma unroll
        for (int r = 0; r < 2; ++r) {
          int row = qrow + r * 32;
          *(f16x8*)(sAB + qn + row * 64 + ((qraw ^ (row & 7)) * 8)) = rq[r];
        }
#pragma unroll
        for (int r = 0; r < 4; ++r) {
          int row = qrow + r * 32;
          *(f16x8*)(sAB + kn + row * 64 + ((qraw ^ (row & 7)) * 8)) = rk[r];
        }
      }
    }

    // ---- Phase B: online softmax (3 barriers) ----
    float mr[16];
#pragma unroll
    for (int r = 0; r < 16; ++r) mr[r] = fmaxf(S[0][r], S[1][r]);
#pragma unroll
    for (int d = 1; d < 32; d <<= 1)
#pragma unroll
      for (int r = 0; r < 16; ++r)
        mr[r] = fmaxf(mr[r], __shfl_xor(mr[r], d, 64));
    if (l31 == 0) {
#pragma unroll
      for (int r = 0; r < 16; ++r) {
        int i = mhalf * 32 + (r & 3) + 8 * (r >> 2) + 4 * lh;
        s_red[i * 2 + npair] = mr[r];
      }
    }
    __syncthreads();
    if (tid < 64) {
      float mc = fmaxf(s_red[tid * 2], s_red[tid * 2 + 1]);
      float mn = fmaxf(s_m[tid], mc);
      s_alpha[tid] = __expf(s_m[tid] - mn);
      s_m[tid] = mn;
    }
    __syncthreads();
    float sr[16];
#pragma unroll
    for (int r = 0; r < 16; ++r) {
      int i = mhalf * 32 + (r & 3) + 8 * (r >> 2) + 4 * lh;
      float m = s_m[i];
      float p0 = __expf(S[0][r] - m);
      float p1 = __expf(S[1][r] - m);
      f16 b0 = (f16)p0, b1 = (f16)p1;
      sP[i * 136 + npair * 64 + l31] = b0;
      sP[i * 136 + npair * 64 + 32 + l31] = b1;
      sr[r] = (float)b0 + (float)b1;              // sum what PV will use
    }
    // prefetch V chunk jc=0 for this wave's private e-rows (hidden by softmax)
    f16x8 rv[2][8];
    const int vrow = lane >> 1 /*x2 rows later*/, dummy0 = 0; (void)dummy0;
#pragma unroll
    for (int r = 0; r < 8; ++r) {
      int gr = lane * 8 + r;
      int row = gr >> 2, of = (gr & 3) * 8;
      rv[0][r] = *(const f16x8*)(vt + vbase + (size_t)(wvx * 128 + row) * NN + j0 + of);
    }
#pragma unroll
    for (int d = 1; d < 32; d <<= 1)
#pragma unroll
      for (int r = 0; r < 16; ++r) sr[r] += __shfl_xor(sr[r], d, 64);
    if (l31 == 0) {
#pragma unroll
      for (int r = 0; r < 16; ++r) {
        int i = mhalf * 32 + (r & 3) + 8 * (r >> 2) + 4 * lh;
        s_red[i * 2 + npair] = sr[r];
      }
    }
#pragma unroll
    for (int mt = 0; mt < 2; ++mt)
#pragma unroll
      for (int r = 0; r < 16; ++r) {
        float a = s_alpha[mt * 32 + (r & 3) + 8 * (r >> 2) + 4 * lh];
#pragma unroll
        for (int nt = 0; nt < 4; ++nt) O[mt][nt][r] *= a;
      }
    __syncthreads();
    if (tid < 64)
      s_l[tid] = s_l[tid] * s_alpha[tid] + s_red[tid * 2] + s_red[tid * 2 + 1];

    // ---- Phase C: O += P.V^T, V via wave-private LDS, no barriers ----
#pragma unroll
    for (int jc = 0; jc < 4; ++jc) {
      // stage current chunk (wave-local: same-wave DS ordering, no barrier)
#pragma unroll
      for (int r = 0; r < 8; ++r) {
        int gr = lane * 8 + r;
        int row = gr >> 2, of = (gr & 3) * 8;
        *(f16x8*)(svw + row * 40 + of) = rv[jc & 1][r];
      }
      if (jc < 3) {
#pragma unroll
        for (int r = 0; r < 8; ++r) {
          int gr = lane * 8 + r;
          int row = gr >> 2, of = (gr & 3) * 8;
          rv[(jc + 1) & 1][r] =
              *(const f16x8*)(vt + vbase + (size_t)(wvx * 128 + row) * NN + j0 + (jc + 1) * 32 + of);
        }
      }
#pragma unroll
      for (int ks = 0; ks < 2; ++ks) {
        f16x8 ap[2];
#pragma unroll
        for (int mt = 0; mt < 2; ++mt)
          ap[mt] = *(const f16x8*)(sP + (mt * 32 + l31) * 136 + jc * 32 + ks * 16 + lh * 8);
#pragma unroll
        for (int nt = 0; nt < 4; ++nt) {
          f16x8 bv = *(const f16x8*)(svw + (nt * 32 + l31) * 40 + ks * 16 + lh * 8);
#pragma unroll
          for (int mt = 0; mt < 2; ++mt)
            O[mt][nt] = mfma16(ap[mt], bv, O[mt][nt]);
        }
      }
    }
  }

  // ---- epilogue: store partial O (fp16, unnormalized) + m,l ----
  const size_t pobase = ((size_t)(jh * NB + b) * NE) * NN;
  if (tid < 64) {
    pm[(jh * NB + b) * NN + i0 + tid] = s_m[tid];
    pl[(jh * NB + b) * NN + i0 + tid] = s_l[tid];
  }
#pragma unroll
  for (int mt = 0; mt < 2; ++mt) {
#pragma unroll
    for (int nt = 0; nt < 4; ++nt) {
      int e = wvx * 128 + nt * 32 + l31;
#pragma unroll
      for (int g = 0; g < 4; ++g) {
        int ib = mt * 32 + g * 8 + 4 * lh;
        f16x4 h4;
#pragma unroll
        for (int j = 0; j < 4; ++j)
          h4[j] = (f16)O[mt][nt][g * 4 + j];
        *(f16x4*)(po + pobase + (size_t)e * NN + i0 + ib) = h4;
      }
    }
  }
}

// ---------------- combine: merge 2 j-halves, divide, add v ----------------
__global__ void combine(const f16* __restrict__ po, const float* __restrict__ pm,
                        const float* __restrict__ pl, const f16* __restrict__ vt,
                        float* __restrict__ out) {
  int id = blockIdx.x * 256 + threadIdx.x;        // NB*NE*NN/4
  int base = id * 4;
  int i  = base % NN;
  int eb = base / NN;                             // b*NE + e
  int b  = eb >> 9;
  const size_t H = (size_t)NB * NE * NN;
  f32x4 m0 = *(const f32x4*)(pm + b * NN + i);
  f32x4 m1 = *(const f32x4*)(pm + NB * NN + b * NN + i);
  f32x4 l0 = *(const f32x4*)(pl + b * NN + i);
  f32x4 l1 = *(const f32x4*)(pl + NB * NN + b * NN + i);
  f16x4 a0 = *(const f16x4*)(po + (size_t)eb * NN + i);
  f16x4 a1 = *(const f16x4*)(po + H + (size_t)eb * NN + i);
  f16x4 vv = *(const f16x4*)(vt + (size_t)eb * NN + i);
  f32x4 res;
#pragma unroll
  for (int j = 0; j < 4; ++j) {
    float m = fmaxf(m0[j], m1[j]);
    float w0 = __expf(m0[j] - m), w1 = __expf(m1[j] - m);
    float l = w0 * l0[j] + w1 * l1[j];
    res[j] = (w0 * (float)a0[j] + w1 * (float)a1[j]) / l + (float)vv[j];
  }
  *(f32x4*)(out + (size_t)eb * NN + i) = res;
}

// ---------------- launch ----------------
extern "C" void kernel_launch(void* const* d_in, const int* in_sizes, int n_in,
                              void* d_out, int out_size, void* d_ws, size_t ws_size,
                              hipStream_t stream) {
  const float* feat = (const float*)d_in[0];
  const float* Wq = (const float*)d_in[1];
  const float* bq = (const float*)d_in[2];
  const float* Wk = (const float*)d_in[3];
  const float* bk = (const float*)d_in[4];
  const float* Wv = (const float*)d_in[5];
  const float* bv = (const float*)d_in[6];
  float* out = (float*)d_out;

  char* ws = (char*)d_ws;
  size_t off = 0;
  auto alloc = [&](size_t bytes) {
    void* p = ws + off;
    off += (bytes + 255) & ~(size_t)255;
    return p;
  };
  const size_t FP = (size_t)NB * HP * HP * NC;     // 5,120,000
  const size_t WP = (size_t)9 * NE * NC;           // 1,179,648
  const size_t QP = (size_t)NB * NN * NE;          // 9,437,184
  f16* fp  = (f16*)alloc(FP * 2);
  f16* wq  = (f16*)alloc(WP * 2);
  f16* wk  = (f16*)alloc(WP * 2);
  f16* wv  = (f16*)alloc(WP * 2);
  f16* q_t = (f16*)alloc(QP * 2);
  f16* k_t = (f16*)alloc(QP * 2);
  f16* v_t = (f16*)alloc(QP * 2);
  f16* po  = (f16*)alloc(2 * QP * 2);              // 37.7 MB partial O
  float* pm = (float*)alloc(2 * (size_t)NB * NN * 4);
  float* pl = (float*)alloc(2 * (size_t)NB * NN * 4);

  pack_feat<<<dim3(FP / 256), dim3(256), 0, stream>>>(feat, fp);
  pack_w<<<dim3(WP / 256), dim3(256), 0, stream>>>(Wq, Wk, Wv, wq, wk, wv);

  conv3_qkv<<<dim3(16, 48), dim3(256), 0, stream>>>(
      fp, wq, wk, wv, bq, bk, bv, q_t, k_t, v_t);

  attn<<<dim3(576), dim3(256), 0, stream>>>(q_t, k_t, v_t, po, pm, pl);
  combine<<<dim3((NB * NE * NN / 4) / 256), dim3(256), 0, stream>>>(po, pm, pl, v_t, out);
}

// Round 7
// 573.419 us; speedup vs baseline: 2.4966x; 1.2950x over previous
//
#include <hip/hip_runtime.h>

// ConvSA: B=8, C=256, H=W=48 (N=2304), E=512.
// out[b,e,i] = sum_j softmax_j(q[:,i].k[:,j]) * v[e,j] + v[e,i]
// All-fp16 operands, fp32 MFMA accumulate. Fused qkv conv (shared X tile,
// reg-prefetched staging, pre-swizzled W). Flash attention: split-j x2,
// XCD-swizzled b; Phase-B softmax via LDS row-transpose (no wave shuffles),
// P stored in A-frag-ordered LDS blocks (conflict-free PV reads); wave-private
// V staging; epilogue LDS-transposed coalesced po stores; combine() merges.
// R6 bug fixed: __syncthreads() between Phase A (q/k LDS reads) and the S
// dump into the aliased sS region.

typedef _Float16 f16;
typedef _Float16 f16x4 __attribute__((ext_vector_type(4)));
typedef _Float16 f16x8 __attribute__((ext_vector_type(8)));
typedef float    f32x4  __attribute__((ext_vector_type(4)));
typedef float    f32x16 __attribute__((ext_vector_type(16)));

__device__ __forceinline__ f32x16 mfma16(f16x8 a, f16x8 b, f32x16 c) {
  return __builtin_amdgcn_mfma_f32_32x32x16_f16(a, b, c, 0, 0, 0);
}

#define NB   8
#define NC   256
#define NH   48
#define NN   2304     // 48*48
#define NE   512
#define HP   50       // padded H/W

// ---------------- pack kernels ----------------

// feat NCHW fp32 -> zero-padded NHWC [b][50][50][256] fp16
__global__ void pack_feat(const float* __restrict__ x, f16* __restrict__ p) {
  int idx = blockIdx.x * 256 + threadIdx.x;       // 8*50*50*256
  int c  = idx & 255;
  int q  = idx >> 8;
  int xp = q % 50; int t = q / 50; int yp = t % 50; int b = t / 50;
  float v = 0.f;
  if (yp >= 1 && yp <= 48 && xp >= 1 && xp <= 48)
    v = x[((b * NC + c) * NH + (yp - 1)) * NH + (xp - 1)];
  p[idx] = (f16)v;
}

// W OIHW [512][256][3][3] fp32 -> A-frag blocks:
// [cc 16][t 9][et 16] x (el 32 x cl 16) contiguous 512-f16 (1 KB) blocks.
__global__ void pack_w(const float* __restrict__ wq, const float* __restrict__ wk,
                       const float* __restrict__ wv,
                       f16* __restrict__ oq, f16* __restrict__ ok,
                       f16* __restrict__ ov) {
  int idx = blockIdx.x * 256 + threadIdx.x;       // 9*512*256
  int c = idx & 255;
  int r = idx >> 8;
  int e = r & 511; int t = r >> 9;
  int src = (e * NC + c) * 9 + t;
  int cc = c >> 4, cl = c & 15, et = e >> 5, el = e & 31;
  int dst = ((cc * 9 + t) * 16 + et) * 512 + el * 16 + cl;
  oq[dst] = (f16)wq[src];
  ok[dst] = (f16)wk[src];
  ov[dst] = (f16)wv[src];
}

// ---------------- fused implicit-GEMM conv3x3 for q,k,v ----------------
// Block 256 thr; out tile 32 e x 384 pos x {q,k,v}; grid (16 e-tiles, 48).
// X chunk register-prefetched (global latency overlapped with MFMA compute);
// W read from pre-swizzled coalesced 1 KB A-frag blocks (L2-resident).
__global__ __launch_bounds__(256, 2) void conv3_qkv(
    const f16* __restrict__ xh,
    const f16* __restrict__ wq, const f16* __restrict__ wk,
    const f16* __restrict__ wv,
    const float* __restrict__ bq, const float* __restrict__ bk,
    const float* __restrict__ bv,
    f16* __restrict__ oq, f16* __restrict__ ok, f16* __restrict__ ov) {
  __shared__ __align__(16) f16 sx[12000];         // 10*50*24

  const int tid = threadIdx.x;
  const int lane = tid & 63, wvx = tid >> 6;
  const int l31 = lane & 31;
  const int koff = (lane >> 5) * 8;
  const int et = blockIdx.x;
  const int e0 = et * 32;
  const int by = blockIdx.y;
  const int b = by / 6, strip = by % 6;
  const int y0 = strip * 8;

  int pb[3];
#pragma unroll
  for (int nt = 0; nt < 3; ++nt) {
    int n = wvx * 96 + nt * 32 + l31;
    pb[nt] = (n / 48) * 50 + (n % 48);
  }

  // staging coords: 4 chunks/thread
  int sgp[4], sgo[4]; bool sok[4]; int gbase[4];
#pragma unroll
  for (int u = 0; u < 4; ++u) {
    int g = u * 256 + tid;
    sok[u] = (g < 1000);
    int gg = sok[u] ? g : 999;
    sgp[u] = gg >> 1; sgo[u] = (gg & 1) * 8;
    int row = sgp[u] / 50, xx = sgp[u] % 50;
    gbase[u] = ((b * HP + y0 + row) * HP + xx) * NC + sgo[u];
  }

  f32x16 acc[3][3];                               // [qkv][nt]
#pragma unroll
  for (int f = 0; f < 3; ++f)
#pragma unroll
    for (int nt = 0; nt < 3; ++nt)
#pragma unroll
      for (int i = 0; i < 16; ++i) acc[f][nt][i] = 0.f;

  f16x8 rx[4];
#pragma unroll
  for (int u = 0; u < 4; ++u)
    rx[u] = *(const f16x8*)(xh + gbase[u]);       // cc=0 prefetch

  const int wlocal = l31 * 16 + koff;

  for (int cc = 0; cc < 16; ++cc) {
    __syncthreads();                              // prev compute done
#pragma unroll
    for (int u = 0; u < 4; ++u)
      if (sok[u]) *(f16x8*)(sx + sgp[u] * 24 + sgo[u]) = rx[u];
    __syncthreads();
    if (cc < 15) {                                // overlap next loads w/ compute
      int c0 = (cc + 1) * 16;
#pragma unroll
      for (int u = 0; u < 4; ++u)
        rx[u] = *(const f16x8*)(xh + gbase[u] + c0);
    }
#pragma unroll
    for (int t = 0; t < 9; ++t) {
      const int dy = t / 3, dx = t % 3;
      const int dpo = (dy * 50 + dx) * 24 + koff;
      f16x8 bh[3];
#pragma unroll
      for (int nt = 0; nt < 3; ++nt)
        bh[nt] = *(const f16x8*)(sx + pb[nt] * 24 + dpo);
      int wb = ((cc * 9 + t) * 16 + et) * 512 + wlocal;
      f16x8 aq = *(const f16x8*)(wq + wb);
      f16x8 ak = *(const f16x8*)(wk + wb);
      f16x8 av = *(const f16x8*)(wv + wb);
#pragma unroll
      for (int nt = 0; nt < 3; ++nt) {
        acc[0][nt] = mfma16(aq, bh[nt], acc[0][nt]);
        acc[1][nt] = mfma16(ak, bh[nt], acc[1][nt]);
        acc[2][nt] = mfma16(av, bh[nt], acc[2][nt]);
      }
    }
  }

  // epilogue: C/D layout col=lane&31 (=pos), row=(r&3)+8*(r>>2)+4*(lane>>5) (=e)
  const int colh = (lane >> 5) * 4;
#pragma unroll
  for (int nt = 0; nt < 3; ++nt) {
    int n = wvx * 96 + nt * 32 + l31;
    int pos = (y0 + n / 48) * 48 + (n % 48);
#pragma unroll
    for (int g = 0; g < 4; ++g) {
      int eb = e0 + g * 8 + colh;
      f32x4 sq = *(const f32x4*)(bq + eb);
      f32x4 sk = *(const f32x4*)(bk + eb);
      f32x4 sv = *(const f32x4*)(bv + eb);
      f16x4 hq, hk;
#pragma unroll
      for (int j = 0; j < 4; ++j) {
        hq[j] = (f16)(acc[0][nt][g * 4 + j] + sq[j]);
        hk[j] = (f16)(acc[1][nt][g * 4 + j] + sk[j]);
        ov[(b * NE + eb + j) * NN + pos] = (f16)(acc[2][nt][g * 4 + j] + sv[j]);
      }
      *(f16x4*)(oq + (b * NN + pos) * NE + eb) = hq;
      *(f16x4*)(ok + (b * NN + pos) * NE + eb) = hk;
    }
  }
}

// ---------------- flash attention (fp16, split-j x2) ----------------
// Grid 576: b = bid&7 (XCD swizzle), jh = (bid>>3)&1, i-tile = bid>>4 (64 rows).
// Phase A: double-buffered q(8KB)/k(16KB) e-chunks in LDS, register prefetch.
// Phase B: S -> LDS (stride 132 fp32, after a barrier!); 4 threads/row
//          reduce+exp+cvt; P written to A-frag blocks sP2[KB][32][8] (rotated).
// Phase C: PV; V staged per-wave (stride 40), register-dbuf; no barriers.
// Epilogue: O transposed via LDS -> coalesced po stores; combine() merges.
__global__ __launch_bounds__(256, 2) void attn(
    const f16* __restrict__ qt, const f16* __restrict__ kt,
    const f16* __restrict__ vt, f16* __restrict__ po,
    float* __restrict__ pm, float* __restrict__ pl) {
  __shared__ __align__(16) f16 sAB[24576];  // A: q dbuf 2x4096 | k dbuf 2x8192
                                            // B: sS fp32 64x132 (alias)
                                            // C: per-wave V: wvx*5120, [128][40]
  __shared__ __align__(16) f16 sP2[8192];   // P A-frag blocks [16 KB]
  __shared__ __align__(16) float s_m[64];
  __shared__ __align__(16) float s_l[64];
  __shared__ __align__(16) float s_alpha[64];

  const int tid = threadIdx.x;
  const int lane = tid & 63, wvx = tid >> 6;
  const int l31 = lane & 31, lh = lane >> 5;
  const int mhalf = wvx >> 1, npair = wvx & 1;
  const int bid = blockIdx.x;
  const int b = bid & 7;
  const int jh = (bid >> 3) & 1;
  const int i0 = (bid >> 4) * 64;

  const int qbase = (b * NN + i0) * NE;
  const int kbase = b * NN * NE;
  const int vbase = b * NE * NN;
  f16* svw = sAB + wvx * 5120;                    // wave-private V region

  if (tid < 64) { s_m[tid] = -3.0e38f; s_l[tid] = 0.f; }

  f32x16 O[2][4];
#pragma unroll
  for (int mt = 0; mt < 2; ++mt)
#pragma unroll
    for (int nt = 0; nt < 4; ++nt)
#pragma unroll
      for (int i = 0; i < 16; ++i) O[mt][nt][i] = 0.f;

  const int qrow = tid >> 3, qraw = tid & 7;      // q/k staging coords
  const int rrow = tid >> 2, qd = tid & 3;        // Phase-B row ownership
  const int mt_r = rrow >> 5, r31 = rrow & 31;

  for (int jt = 0; jt < 9; ++jt) {
    const int j0 = jh * 1152 + jt * 128;
    f32x16 S[2];
#pragma unroll
    for (int nt = 0; nt < 2; ++nt)
#pragma unroll
      for (int i = 0; i < 16; ++i) S[nt][i] = 0.f;

    f16x8 rq[2], rk[4];
    // prologue: prefetch e-chunk 0, then barrier (prev Phase C done), store.
#pragma unroll
    for (int r = 0; r < 2; ++r)
      rq[r] = *(const f16x8*)(qt + qbase + (qrow + r * 32) * NE + qraw * 8);
#pragma unroll
    for (int r = 0; r < 4; ++r)
      rk[r] = *(const f16x8*)(kt + kbase + (j0 + qrow + r * 32) * NE + qraw * 8);
    __syncthreads();
#pragma unroll
    for (int r = 0; r < 2; ++r) {
      int row = qrow + r * 32;
      *(f16x8*)(sAB + row * 64 + ((qraw ^ (row & 7)) * 8)) = rq[r];
    }
#pragma unroll
    for (int r = 0; r < 4; ++r) {
      int row = qrow + r * 32;
      *(f16x8*)(sAB + 8192 + row * 64 + ((qraw ^ (row & 7)) * 8)) = rk[r];
    }

    // ---- Phase A: S = q.k^T, 8 e-chunks of 64, double-buffered ----
    for (int ec = 0; ec < 8; ++ec) {
      __syncthreads();
      const bool pf = (ec < 7);
      if (pf) {
#pragma unroll
        for (int r = 0; r < 2; ++r)
          rq[r] = *(const f16x8*)(qt + qbase + (qrow + r * 32) * NE + (ec + 1) * 64 + qraw * 8);
#pragma unroll
        for (int r = 0; r < 4; ++r)
          rk[r] = *(const f16x8*)(kt + kbase + (j0 + qrow + r * 32) * NE + (ec + 1) * 64 + qraw * 8);
      }
      const int qcur = (ec & 1) * 4096;
      const int kcur = 8192 + (ec & 1) * 8192;
      const int irow = mhalf * 32 + l31;
#pragma unroll
      for (int ks = 0; ks < 4; ++ks) {
        f16x8 aq = *(const f16x8*)(sAB + qcur + irow * 64 + (((ks * 2 + lh) ^ (irow & 7)) * 8));
#pragma unroll
        for (int nt = 0; nt < 2; ++nt) {
          int jrow = npair * 64 + nt * 32 + l31;
          f16x8 bk = *(const f16x8*)(sAB + kcur + jrow * 64 + (((ks * 2 + lh) ^ (jrow & 7)) * 8));
          S[nt] = mfma16(aq, bk, S[nt]);
        }
      }
      if (pf) {
        const int qn = ((ec + 1) & 1) * 4096;
        const int kn = 8192 + ((ec + 1) & 1) * 8192;
#pragma unroll
        for (int r = 0; r < 2; ++r) {
          int row = qrow + r * 32;
          *(f16x8*)(sAB + qn + row * 64 + ((qraw ^ (row & 7)) * 8)) = rq[r];
        }
#pragma unroll
        for (int r = 0; r < 4; ++r) {
          int row = qrow + r * 32;
          *(f16x8*)(sAB + kn + row * 64 + ((qraw ^ (row & 7)) * 8)) = rk[r];
        }
      }
    }

    // ---- Phase B: softmax via LDS row-transpose ----
    __syncthreads();                  // Phase-A q/k LDS reads done (sS aliases!)
    float* sS = (float*)sAB;
#pragma unroll
    for (int nt = 0; nt < 2; ++nt)
#pragma unroll
      for (int r = 0; r < 16; ++r) {
        int ii = mhalf * 32 + (r & 3) + 8 * (r >> 2) + 4 * lh;
        int jj = npair * 64 + nt * 32 + l31;
        sS[ii * 132 + jj] = S[nt][r];
      }
    __syncthreads();
    // prefetch V chunk jc=0 (hidden under the reduction)
    f16x8 rv[2][8];
#pragma unroll
    for (int r = 0; r < 8; ++r) {
      int gr = lane * 8 + r;
      int row = gr >> 2, of = (gr & 3) * 8;
      rv[0][r] = *(const f16x8*)(vt + vbase + (size_t)(wvx * 128 + row) * NN + j0 + of);
    }
    float vals[32];
#pragma unroll
    for (int c = 0; c < 4; ++c) {
      f32x4 a0 = *(const f32x4*)(sS + rrow * 132 + qd * 8 + 32 * c);
      f32x4 a1 = *(const f32x4*)(sS + rrow * 132 + qd * 8 + 32 * c + 4);
#pragma unroll
      for (int u = 0; u < 4; ++u) {
        vals[c * 8 + u] = a0[u];
        vals[c * 8 + 4 + u] = a1[u];
      }
    }
    float mx = vals[0];
#pragma unroll
    for (int u = 1; u < 32; ++u) mx = fmaxf(mx, vals[u]);
    mx = fmaxf(mx, __shfl_xor(mx, 1, 64));
    mx = fmaxf(mx, __shfl_xor(mx, 2, 64));
    float mold = s_m[rrow];
    float mnew = fmaxf(mold, mx);
    float alpha = __expf(mold - mnew);
    float sum = 0.f;
#pragma unroll
    for (int c = 0; c < 4; ++c) {
      f16x8 pc;
#pragma unroll
      for (int u = 0; u < 8; ++u) {
        f16 ph = (f16)__expf(vals[c * 8 + u] - mnew);
        pc[u] = ph;
        sum += (float)ph;
      }
      int kc = (qd >> 1) + 2 * c;
      int KB = (kc * 2 + mt_r) * 2 + (qd & 1);
      *(f16x8*)(sP2 + KB * 256 + (((r31 + KB * 4) & 31) * 8)) = pc;
    }
    sum += __shfl_xor(sum, 1, 64);
    sum += __shfl_xor(sum, 2, 64);
    if (qd == 0) {
      s_alpha[rrow] = alpha;
      s_m[rrow] = mnew;
      s_l[rrow] = s_l[rrow] * alpha + sum;
    }
    __syncthreads();
    // rescale O
#pragma unroll
    for (int mt = 0; mt < 2; ++mt)
#pragma unroll
      for (int g = 0; g < 4; ++g) {
        f32x4 al = *(const f32x4*)(s_alpha + mt * 32 + g * 8 + 4 * lh);
#pragma unroll
        for (int j2 = 0; j2 < 4; ++j2) {
          float a = al[j2];
#pragma unroll
          for (int nt = 0; nt < 4; ++nt) O[mt][nt][g * 4 + j2] *= a;
        }
      }

    // ---- Phase C: O += P.V^T, V via wave-private LDS, no barriers ----
#pragma unroll
    for (int jc = 0; jc < 4; ++jc) {
#pragma unroll
      for (int r = 0; r < 8; ++r) {
        int gr = lane * 8 + r;
        int row = gr >> 2, of = (gr & 3) * 8;
        *(f16x8*)(svw + row * 40 + of) = rv[jc & 1][r];
      }
      if (jc < 3) {
#pragma unroll
        for (int r = 0; r < 8; ++r) {
          int gr = lane * 8 + r;
          int row = gr >> 2, of = (gr & 3) * 8;
          rv[(jc + 1) & 1][r] =
              *(const f16x8*)(vt + vbase + (size_t)(wvx * 128 + row) * NN + j0 + (jc + 1) * 32 + of);
        }
      }
#pragma unroll
      for (int ks = 0; ks < 2; ++ks) {
        f16x8 ap[2];
#pragma unroll
        for (int mt = 0; mt < 2; ++mt) {
          int KB = ((jc * 2 + ks) * 2 + mt) * 2 + lh;
          ap[mt] = *(const f16x8*)(sP2 + KB * 256 + (((l31 + KB * 4) & 31) * 8));
        }
#pragma unroll
        for (int nt = 0; nt < 4; ++nt) {
          f16x8 bv = *(const f16x8*)(svw + (nt * 32 + l31) * 40 + ks * 16 + lh * 8);
#pragma unroll
          for (int mt = 0; mt < 2; ++mt)
            O[mt][nt] = mfma16(ap[mt], bv, O[mt][nt]);
        }
      }
    }
  }

  // ---- epilogue: m,l + LDS-transposed coalesced po stores ----
  __syncthreads();                                // all svw/sP2 readers done
  if (tid < 64) {
    pm[(jh * NB + b) * NN + i0 + tid] = s_m[tid];
    pl[(jh * NB + b) * NN + i0 + tid] = s_l[tid];
  }
  const size_t pobase = ((size_t)(jh * NB + b) * NE) * NN;
  f16* sT = sAB + wvx * 4608;                     // 128 e x stride 36 f16 / wave
#pragma unroll
  for (int mt = 0; mt < 2; ++mt) {
#pragma unroll
    for (int nt = 0; nt < 4; ++nt) {
      int el = nt * 32 + l31;
#pragma unroll
      for (int g = 0; g < 4; ++g) {
        f16x4 h4;
#pragma unroll
        for (int j2 = 0; j2 < 4; ++j2)
          h4[j2] = (f16)O[mt][nt][g * 4 + j2];
        *(f16x4*)(sT + el * 36 + g * 8 + 4 * lh) = h4;
      }
    }
#pragma unroll
    for (int rr = 0; rr < 16; ++rr) {
      int el = rr * 8 + (lane >> 3);
      int iq = lane & 7;
      f16x4 t4 = *(const f16x4*)(sT + el * 36 + iq * 4);
      *(f16x4*)(po + pobase + (size_t)(wvx * 128 + el) * NN + i0 + mt * 32 + iq * 4) = t4;
    }
  }
}

// ---------------- combine: merge 2 j-halves, divide, add v ----------------
__global__ void combine(const f16* __restrict__ po, const float* __restrict__ pm,
                        const float* __restrict__ pl, const f16* __restrict__ vt,
                        float* __restrict__ out) {
  int id = blockIdx.x * 256 + threadIdx.x;        // NB*NE*NN/4
  int base = id * 4;
  int i  = base % NN;
  int eb = base / NN;                             // b*NE + e
  int b  = eb >> 9;
  const size_t H = (size_t)NB * NE * NN;
  f32x4 m0 = *(const f32x4*)(pm + b * NN + i);
  f32x4 m1 = *(const f32x4*)(pm + NB * NN + b * NN + i);
  f32x4 l0 = *(const f32x4*)(pl + b * NN + i);
  f32x4 l1 = *(const f32x4*)(pl + NB * NN + b * NN + i);
  f16x4 a0 = *(const f16x4*)(po + (size_t)eb * NN + i);
  f16x4 a1 = *(const f16x4*)(po + H + (size_t)eb * NN + i);
  f16x4 vv = *(const f16x4*)(vt + (size_t)eb * NN + i);
  f32x4 res;
#pragma unroll
  for (int j = 0; j < 4; ++j) {
    float m = fmaxf(m0[j], m1[j]);
    float w0 = __expf(m0[j] - m), w1 = __expf(m1[j] - m);
    float l = w0 * l0[j] + w1 * l1[j];
    res[j] = (w0 * (float)a0[j] + w1 * (float)a1[j]) / l + (float)vv[j];
  }
  *(f32x4*)(out + (size_t)eb * NN + i) = res;
}

// ---------------- launch ----------------
extern "C" void kernel_launch(void* const* d_in, const int* in_sizes, int n_in,
                              void* d_out, int out_size, void* d_ws, size_t ws_size,
                              hipStream_t stream) {
  const float* feat = (const float*)d_in[0];
  const float* Wq = (const float*)d_in[1];
  const float* bq = (const float*)d_in[2];
  const float* Wk = (const float*)d_in[3];
  const float* bk = (const float*)d_in[4];
  const float* Wv = (const float*)d_in[5];
  const float* bv = (const float*)d_in[6];
  float* out = (float*)d_out;

  char* ws = (char*)d_ws;
  size_t off = 0;
  auto alloc = [&](size_t bytes) {
    void* p = ws + off;
    off += (bytes + 255) & ~(size_t)255;
    return p;
  };
  const size_t FP = (size_t)NB * HP * HP * NC;     // 5,120,000
  const size_t WP = (size_t)9 * NE * NC;           // 1,179,648
  const size_t QP = (size_t)NB * NN * NE;          // 9,437,184
  f16* fp  = (f16*)alloc(FP * 2);
  f16* wq  = (f16*)alloc(WP * 2);
  f16* wk  = (f16*)alloc(WP * 2);
  f16* wv  = (f16*)alloc(WP * 2);
  f16* q_t = (f16*)alloc(QP * 2);
  f16* k_t = (f16*)alloc(QP * 2);
  f16* v_t = (f16*)alloc(QP * 2);
  f16* po  = (f16*)alloc(2 * QP * 2);              // 37.7 MB partial O
  float* pm = (float*)alloc(2 * (size_t)NB * NN * 4);
  float* pl = (float*)alloc(2 * (size_t)NB * NN * 4);

  pack_feat<<<dim3(FP / 256), dim3(256), 0, stream>>>(feat, fp);
  pack_w<<<dim3(WP / 256), dim3(256), 0, stream>>>(Wq, Wk, Wv, wq, wk, wv);

  conv3_qkv<<<dim3(16, 48), dim3(256), 0, stream>>>(
      fp, wq, wk, wv, bq, bk, bv, q_t, k_t, v_t);

  attn<<<dim3(576), dim3(256), 0, stream>>>(q_t, k_t, v_t, po, pm, pl);
  combine<<<dim3((NB * NE * NN / 4) / 256), dim3(256), 0, stream>>>(po, pm, pl, v_t, out);
}